// Round 5
// baseline (900.347 us; speedup 1.0000x reference)
//
#include <hip/hip_runtime.h>
#include <stdint.h>

#define THRESH_ 0.3f
constexpr int B_ = 256, WIN_ = 100, NIN_ = 700, NINP_ = 704, H_ = 512;
constexpr int NOUT_ = 20, NOUTP_ = 32, ND_ = 10, KBIG_ = 5120, M_ = 25600;
constexpr int PLANES_ = 140;  // 40 zero-history + 100
constexpr int KQ_ = 10240;    // limb-duplicated K for the 8-phase spike GEMM
constexpr int KT_SPK = KQ_ / 64;  // 160 K-tiles

typedef unsigned short u16;
typedef unsigned int u32;
typedef unsigned short u16x8 __attribute__((ext_vector_type(8)));
typedef float f32x4 __attribute__((ext_vector_type(4)));

// ---- fp16 RNE split ----
__device__ __forceinline__ u16 f2h(float f) {
  _Float16 h = (_Float16)f;           // RNE
  union { _Float16 h; u16 u; } v; v.h = h;
  return v.u;
}
__device__ __forceinline__ float h2f(u16 u) {
  union { u16 u; _Float16 h; } v; v.u = u;
  return (float)v.h;
}

__device__ __forceinline__ void mfma_h(f32x4& acc, u16x8 a, u16x8 b) {
  asm volatile("v_mfma_f32_16x16x32_f16 %0, %1, %2, %0" : "+v"(acc) : "v"(a), "v"(b));
}
__device__ __forceinline__ void gload16(const void* g, void* l) {
  __builtin_amdgcn_global_load_lds(
      (const __attribute__((address_space(1))) unsigned int*)g,
      (__attribute__((address_space(3))) unsigned int*)l, 16, 0, 0);
}

// ---------------- weight / input prep ----------------

__global__ void k_split_x(const float* __restrict__ in, u16* __restrict__ xh, u16* __restrict__ xl) {
  int k = blockIdx.x * 64 + threadIdx.x;   // [0,704)
  int r = blockIdx.y;                      // r = t*256 + b
  int t = r >> 8, b = r & 255;
  float v = (k < NIN_) ? in[(b * WIN_ + t) * NIN_ + k] : 0.f;
  u16 h = f2h(v);
  u16 lo = f2h(v - h2f(h));
  xh[r * NINP_ + k] = h;
  xl[r * NINP_ + k] = lo;
}

__global__ void k_split_w0(const float* __restrict__ w, u16* __restrict__ wh, u16* __restrict__ wl) {
  int k = blockIdx.x * 64 + threadIdx.x;   // [0,704)
  int j = blockIdx.y;                      // [0,512)
  float v = (k < NIN_) ? w[j * NIN_ + k] * 256.0f : 0.f;  // scale keeps low limb normal
  u16 h = f2h(v);
  u16 lo = f2h(v - h2f(h));
  wh[j * NINP_ + k] = h;
  wl[j * NINP_ + k] = lo;
}

// permute K: k' = d*512 + h  <-  reference col h*10 + d; 2-limb fp16 interleaved along K'
// W1q u16 layout [512][10240]: [j][2k+0]=hi, [2k+1]=lo   (stored as one u32 per k)
__global__ void k_permsplit_w1q(const float* __restrict__ w, u32* __restrict__ wq) {
  int k = blockIdx.x * 64 + threadIdx.x;   // [0,5120)
  int j = blockIdx.y;                      // [0,512)
  int d = k >> 9, h = k & 511;
  float v = w[j * KBIG_ + h * ND_ + d] * 256.0f;
  u16 a = f2h(v);
  u16 b = f2h(v - h2f(a));
  wq[j * KBIG_ + k] = ((u32)b << 16) | a;
}

__global__ void k_permsplit_wo(const float* __restrict__ w, u16* __restrict__ wh, u16* __restrict__ wl) {
  int k = blockIdx.x * 64 + threadIdx.x;   // [0,5120)
  int j = blockIdx.y;                      // [0,32)
  int d = k >> 9, h = k & 511;
  float v = (j < NOUT_) ? w[j * KBIG_ + h * ND_ + d] * 256.0f : 0.f;
  u16 a = f2h(v);
  u16 b = f2h(v - h2f(a));
  wh[j * KBIG_ + k] = a;
  wl[j * KBIG_ + k] = b;
}

// ---------------- GEMM 0: cur1 = X @ W0^T  (fp16 2x2 split, 4 terms, BK=32) ----------------

__global__ __launch_bounds__(256) void k_gemm0(const u16* __restrict__ Xh, const u16* __restrict__ Xl,
                                               const u16* __restrict__ Wh, const u16* __restrict__ Wl,
                                               float* __restrict__ out) {
  __shared__ alignas(16) u16 lAh[128 * 32], lAl[128 * 32], lBh[128 * 32], lBl[128 * 32];
  const int tid = threadIdx.x, lane = tid & 63, wid = tid >> 6;
  const int m0 = blockIdx.y * 128, n0 = blockIdx.x * 128;
  const int wr = wid >> 1, wc = wid & 1;
  const int srow = lane >> 2;
  const int sk = 8 * ((lane & 3) ^ ((lane >> 3) & 3));  // source-side XOR swizzle (16B units)
  const int fr = lane & 15, kb = lane >> 4;
  int aoff[4], boff[4];
#pragma unroll
  for (int f = 0; f < 4; f++) {
    int row = wr * 64 + f * 16 + fr;
    aoff[f] = row * 32 + (kb ^ ((row >> 1) & 3)) * 8;
    int col = wc * 64 + f * 16 + fr;
    boff[f] = col * 32 + (kb ^ ((col >> 1) & 3)) * 8;
  }
  f32x4 acc[4][4] = {};
#pragma unroll 1
  for (int kk = 0; kk < NINP_ / 32; kk++) {
    const int k0 = kk * 32;
#pragma unroll
    for (int i = 0; i < 2; i++) {
      int c = wid + 4 * i;
      int ga = (m0 + c * 16 + srow) * NINP_ + k0 + sk;
      gload16(Xh + ga, &lAh[c * 512]);
      gload16(Xl + ga, &lAl[c * 512]);
      int gb = (n0 + c * 16 + srow) * NINP_ + k0 + sk;
      gload16(Wh + gb, &lBh[c * 512]);
      gload16(Wl + gb, &lBl[c * 512]);
    }
    asm volatile("s_waitcnt vmcnt(0)" ::: "memory");
    __syncthreads();
    u16x8 bh[4], bl[4];
#pragma unroll
    for (int j = 0; j < 4; j++) {
      bh[j] = *(const u16x8*)&lBh[boff[j]];
      bl[j] = *(const u16x8*)&lBl[boff[j]];
    }
#pragma unroll
    for (int i = 0; i < 4; i++) {
      u16x8 ah = *(const u16x8*)&lAh[aoff[i]];
      u16x8 al = *(const u16x8*)&lAl[aoff[i]];
#pragma unroll
      for (int j = 0; j < 4; j++) {
        mfma_h(acc[i][j], ah, bh[j]);
        mfma_h(acc[i][j], ah, bl[j]);
        mfma_h(acc[i][j], al, bh[j]);
        mfma_h(acc[i][j], al, bl[j]);
      }
    }
    __syncthreads();
  }
  asm volatile("s_nop 7\n\ts_nop 7" ::: "memory");
#pragma unroll
  for (int i = 0; i < 4; i++) {
    int row = m0 + wr * 64 + i * 16 + (lane >> 4) * 4;
#pragma unroll
    for (int j = 0; j < 4; j++) {
      int col = n0 + wc * 64 + j * 16 + fr;
#pragma unroll
      for (int r = 0; r < 4; r++)
        out[(row + r) * H_ + col] = acc[i][j][r] * (1.0f / 256.0f);  // undo W0 scale (exact)
    }
  }
}

// ---------------- GEMM spk (8-phase 256x256): cur2 = gather(S1q) @ W1q^T ----------------
// A = duplicated spikes [140 planes][256][1024], B = W1q [512][10240]. K' = 10240.
// LDS [dbuf][kh][256 rows][32 u16] per operand; 64B row stride + slot XOR (j^row&3)
// => zero-conflict ds_read_b128. Staged via pre-swizzled global source (linear LDS dest).
// Schedule per K-tile: 4 phases (kh,mh), counted vmcnt(4) at ph1/ph3 (never 0 mid-loop).

__global__ __launch_bounds__(512) void k_gemm8_spk(const u16* __restrict__ Aq,
                                                   const u16* __restrict__ Bq,
                                                   float* __restrict__ out) {
  __shared__ alignas(16) u16 sA[2][2][256][32];  // 64 KB
  __shared__ alignas(16) u16 sB[2][2][256][32];  // 64 KB
  u16* sAf = &sA[0][0][0][0];
  u16* sBf = &sB[0][0][0][0];
  const int tid = threadIdx.x;
  const int lane = tid & 63, wid = tid >> 6;   // 8 waves
  const int wm = wid >> 2, wn = wid & 3;       // 2 x 4 wave grid
  const int fr = lane & 15, kb = lane >> 4;
  const int t = blockIdx.y;                    // one t per M-tile (256 rows = batch)
  const int n0 = blockIdx.x * 256;

  // staging lane mapping: chunk = 16 rows x 64B; rr = row-in-chunk, swz8 = src k-slot
  const int rr = lane >> 2;
  const int swz8 = ((lane & 3) ^ ((lane >> 2) & 3)) * 8;

  // fragment read offsets (u16 units within one [256][32] region)
  int aro[8], bro[4];
#pragma unroll
  for (int f = 0; f < 8; f++) aro[f] = (wm * 128 + f * 16 + fr) * 32 + ((kb ^ (fr & 3)) * 8);
#pragma unroll
  for (int f = 0; f < 4; f++) bro[f] = (wn * 64 + f * 16 + fr) * 32 + ((kb ^ (fr & 3)) * 8);

  f32x4 acc[8][4] = {};

  // stage one (operand, kh) unit of tile kt_ into buffer buf: 2 gloads per wave
#define STAGE_A(buf, kt_, kh_) do { \
    int k0s = (kt_) * 64; \
    const u16* baseA = Aq + (size_t)((t + 4 * (k0s >> 10)) * 256) * 1024 + (k0s & 1023) + (kh_) * 32 + swz8; \
    u16* dstA = &sA[(buf)][(kh_)][0][0]; \
    gload16(baseA + (size_t)(wid * 16 + rr) * 1024, dstA + (wid * 16) * 32); \
    gload16(baseA + (size_t)((wid + 8) * 16 + rr) * 1024, dstA + ((wid + 8) * 16) * 32); \
  } while (0)
#define STAGE_B(buf, kt_, kh_) do { \
    int k0s = (kt_) * 64; \
    const u16* baseB = Bq + (size_t)(n0) * KQ_ + k0s + (kh_) * 32 + swz8; \
    u16* dstB = &sB[(buf)][(kh_)][0][0]; \
    gload16(baseB + (size_t)(wid * 16 + rr) * KQ_, dstB + (wid * 16) * 32); \
    gload16(baseB + (size_t)((wid + 8) * 16 + rr) * KQ_, dstB + ((wid + 8) * 16) * 32); \
  } while (0)

#define PHASE(c_, kh_, mh_, STG, W4) do { \
    const int rg = ((c_) * 2 + (kh_)) * 8192; \
    u16x8 av[4], bv[4]; \
    _Pragma("unroll") for (int nf = 0; nf < 4; ++nf) bv[nf] = *(const u16x8*)&sBf[rg + bro[nf]]; \
    _Pragma("unroll") for (int mf = 0; mf < 4; ++mf) av[mf] = *(const u16x8*)&sAf[rg + aro[(mh_) * 4 + mf]]; \
    STG; \
    __builtin_amdgcn_s_barrier(); \
    __builtin_amdgcn_s_setprio(1); \
    _Pragma("unroll") for (int mf = 0; mf < 4; ++mf) { \
      _Pragma("unroll") for (int nf = 0; nf < 4; ++nf) mfma_h(acc[(mh_) * 4 + mf][nf], av[mf], bv[nf]); \
    } \
    __builtin_amdgcn_s_setprio(0); \
    if (W4) asm volatile("s_waitcnt vmcnt(4)" ::: "memory"); \
    __builtin_amdgcn_s_barrier(); \
  } while (0)

  // prologue: stage tile 0 fully into buf 0; wait for its kh=0 units
  STAGE_A(0, 0, 0);
  STAGE_B(0, 0, 0);
  STAGE_A(0, 0, 1);
  STAGE_B(0, 0, 1);
  asm volatile("s_waitcnt vmcnt(4)" ::: "memory");
  __builtin_amdgcn_s_barrier();

#pragma unroll 1
  for (int kt = 0; kt < KT_SPK; ++kt) {
    const int c = kt & 1, nb = c ^ 1;
    const int ktn = (kt + 1 < KT_SPK) ? kt + 1 : kt;  // redundant re-stage keeps vmcnt uniform
    PHASE(c, 0, 0, STAGE_A(nb, ktn, 0), 0);
    PHASE(c, 0, 1, STAGE_B(nb, ktn, 0), 1);  // vmcnt(4): A1,B1 of tile kt landed
    PHASE(c, 1, 0, STAGE_A(nb, ktn, 1), 0);
    PHASE(c, 1, 1, STAGE_B(nb, ktn, 1), 1);  // vmcnt(4): A0,B0 of tile kt+1 landed
  }
#undef PHASE
#undef STAGE_A
#undef STAGE_B

  asm volatile("s_nop 7\n\ts_nop 7" ::: "memory");
#pragma unroll
  for (int i = 0; i < 8; i++) {
    int row = t * 256 + wm * 128 + i * 16 + kb * 4;
#pragma unroll
    for (int j = 0; j < 4; j++) {
      int col = n0 + wn * 64 + j * 16 + fr;
#pragma unroll
      for (int r = 0; r < 4; r++)
        out[(size_t)(row + r) * H_ + col] = acc[i][j][r] * (1.0f / 256.0f);  // undo W1 scale
    }
  }
}

// ---------------- GEMM out: curo = gather(S2) @ Wop^T  (N=32 padded, 2-limb, BK=32) ----------------

__global__ __launch_bounds__(256) void k_gemm_out(const u16* __restrict__ S, const u16* __restrict__ Wh,
                                                  const u16* __restrict__ Wl, float* __restrict__ out) {
  __shared__ alignas(16) u16 lA[128 * 32], lBh[32 * 32], lBl[32 * 32];
  const int tid = threadIdx.x, lane = tid & 63, wid = tid >> 6;
  const int mt = blockIdx.x;
  const int m0 = mt * 128;
  const int t = mt >> 1, brow0 = (mt & 1) * 128;
  const int srow = lane >> 2;
  const int sk = 8 * ((lane & 3) ^ ((lane >> 3) & 3));
  const int fr = lane & 15, kb = lane >> 4;
  int aoff[2], boff[2];
#pragma unroll
  for (int f = 0; f < 2; f++) {
    int row = wid * 32 + f * 16 + fr;
    aoff[f] = row * 32 + (kb ^ ((row >> 1) & 3)) * 8;
    int col = f * 16 + fr;
    boff[f] = col * 32 + (kb ^ ((col >> 1) & 3)) * 8;
  }
  f32x4 acc[2][2] = {};
#pragma unroll 1
  for (int kk = 0; kk < KBIG_ / 32; kk++) {
    const int k0 = kk * 32;
    const int d = k0 >> 9, h0 = k0 & 511;
    const int p = t + 4 * d;
#pragma unroll
    for (int i = 0; i < 2; i++) {
      int c = wid + 4 * i;
      gload16(S + ((size_t)(p * 256 + brow0 + c * 16 + srow) * 512 + h0 + sk), &lA[c * 512]);
    }
    {  // 4 B chunks (2 buffers x 2 halves) over 4 waves
      const u16* bs = (wid < 2) ? Wh : Wl;
      u16* bd = (wid < 2) ? (u16*)lBh : (u16*)lBl;
      int half = wid & 1;
      gload16(bs + (size_t)(half * 16 + srow) * KBIG_ + k0 + sk, &bd[half * 512]);
    }
    asm volatile("s_waitcnt vmcnt(0)" ::: "memory");
    __syncthreads();
    u16x8 bh[2], bl[2];
#pragma unroll
    for (int j = 0; j < 2; j++) {
      bh[j] = *(const u16x8*)&lBh[boff[j]];
      bl[j] = *(const u16x8*)&lBl[boff[j]];
    }
#pragma unroll
    for (int i = 0; i < 2; i++) {
      u16x8 a = *(const u16x8*)&lA[aoff[i]];
#pragma unroll
      for (int j = 0; j < 2; j++) {
        mfma_h(acc[i][j], a, bh[j]);
        mfma_h(acc[i][j], a, bl[j]);
      }
    }
    __syncthreads();
  }
  asm volatile("s_nop 7\n\ts_nop 7" ::: "memory");
#pragma unroll
  for (int i = 0; i < 2; i++) {
    int row = m0 + wid * 32 + i * 16 + (lane >> 4) * 4;
#pragma unroll
    for (int j = 0; j < 2; j++) {
      int col = j * 16 + fr;
#pragma unroll
      for (int r = 0; r < 4; r++)
        out[(row + r) * NOUTP_ + col] = acc[i][j][r] * (1.0f / 256.0f);  // undo Wo scale
    }
  }
}

// ---------------- elementwise LIF scans (strict fp32 rounding, no contraction) ----------------

// layer 1: writes duplicated fp16 spike pairs (u32) for the 8-phase GEMM
__global__ void k_scan1(const float* __restrict__ cur, const float* __restrict__ tau, u32* __restrict__ Sq) {
  int g = blockIdx.x * 256 + threadIdx.x;   // [0, 131072)
  int b = g >> 9, h = g & 511;
  float a = (float)(1.0 / (1.0 + exp(-(double)tau[h])));
  float mem = 0.f, s = 0.f;
#pragma unroll 1
  for (int t = 0; t < WIN_; t++) {
    float c = cur[(t * 256 + b) * 512 + h];
    mem = __fadd_rn(__fmul_rn(__fmul_rn(mem, a), __fsub_rn(1.f, s)), c);
    float x = __fsub_rn(mem, THRESH_);
    s = (x > 0.f) ? 1.f : 0.f;
    mem = (mem < THRESH_) ? mem : 0.f;
    Sq[((t + 40) * 256 + b) * 512 + h] = (x > 0.f) ? 0x3C003C00u : 0u;  // fp16 1.0 pair
  }
}

// layer 2: plain fp16 spikes for gemm_out
__global__ void k_scan2(const float* __restrict__ cur, const float* __restrict__ tau, u16* __restrict__ S) {
  int g = blockIdx.x * 256 + threadIdx.x;   // [0, 131072)
  int b = g >> 9, h = g & 511;
  float a = (float)(1.0 / (1.0 + exp(-(double)tau[h])));
  float mem = 0.f, s = 0.f;
#pragma unroll 1
  for (int t = 0; t < WIN_; t++) {
    float c = cur[(t * 256 + b) * 512 + h];
    mem = __fadd_rn(__fmul_rn(__fmul_rn(mem, a), __fsub_rn(1.f, s)), c);
    float x = __fsub_rn(mem, THRESH_);
    s = (x > 0.f) ? 1.f : 0.f;
    mem = (mem < THRESH_) ? mem : 0.f;
    S[((t + 40) * 256 + b) * 512 + h] = (x > 0.f) ? (u16)0x3C00 : (u16)0;  // fp16 1.0
  }
}

__global__ void k_scan_o(const float* __restrict__ curo, const float* __restrict__ tau, float* __restrict__ outp) {
  int b = blockIdx.x * 64 + threadIdx.x;
  if (b >= B_) return;
  float ao[NOUT_], mem[NOUT_], spk[NOUT_], osum[NOUT_], mot[NOUT_];
#pragma unroll
  for (int j = 0; j < NOUT_; j++) {
    ao[j] = (float)(1.0 / (1.0 + exp(-(double)tau[j])));
    mem[j] = 0.f; spk[j] = 0.f; osum[j] = 0.f; mot[j] = 0.f;
  }
#pragma unroll 1
  for (int t = 0; t < WIN_; t++) {
    const float4* rowp = (const float4*)&curo[(t * 256 + b) * NOUTP_];
    float4 v[5];
#pragma unroll
    for (int q = 0; q < 5; q++) v[q] = rowp[q];
    float cv[NOUT_];
#pragma unroll
    for (int q = 0; q < 5; q++) {
      cv[4 * q + 0] = v[q].x; cv[4 * q + 1] = v[q].y;
      cv[4 * q + 2] = v[q].z; cv[4 * q + 3] = v[q].w;
    }
#pragma unroll
    for (int j = 0; j < NOUT_; j++) {
      mem[j] = __fadd_rn(__fmul_rn(__fmul_rn(mem[j], ao[j]), __fsub_rn(1.f, spk[j])), cv[j]);
      float x = __fsub_rn(mem[j], THRESH_);
      spk[j] = (x > 0.f) ? 1.f : 0.f;
      mem[j] = (mem[j] < THRESH_) ? mem[j] : 0.f;
      osum[j] = __fadd_rn(osum[j], spk[j]);
    }
    float mx = -1e30f;
#pragma unroll
    for (int j = 0; j < NOUT_; j++) mx = fmaxf(mx, mem[j]);
    float se = 0.f, e[NOUT_];
#pragma unroll
    for (int j = 0; j < NOUT_; j++) { e[j] = expf(__fsub_rn(mem[j], mx)); se = __fadd_rn(se, e[j]); }
#pragma unroll
    for (int j = 0; j < NOUT_; j++) mot[j] = __fadd_rn(mot[j], __fdiv_rn(e[j], se));
  }
#pragma unroll
  for (int j = 0; j < NOUT_; j++) {
    outp[b * NOUT_ + j] = __fdiv_rn(osum[j], 100.0f);
    outp[B_ * NOUT_ + b * NOUT_ + j] = mot[j];
  }
}

// ---------------- launch ----------------
// Workspace aliasing (liveness-based, keeps footprint ~214MB < 266MB proven in R3):
//   region0 (72.1MB): Xh+Xl   -> dead after k_gemm0   -> reused as cur2 (52.4MB)
//   region1 (52.4MB): cur1    -> dead after k_scan1   -> reused as S2   (36.7MB)

extern "C" void kernel_launch(void* const* d_in, const int* in_sizes, int n_in,
                              void* d_out, int out_size, void* d_ws, size_t ws_size,
                              hipStream_t stream) {
  const float* in   = (const float*)d_in[0];
  const float* W0   = (const float*)d_in[1];
  const float* W1   = (const float*)d_in[2];
  const float* Wo   = (const float*)d_in[3];
  const float* tau1 = (const float*)d_in[4];
  const float* tau2 = (const float*)d_in[5];
  const float* tauo = (const float*)d_in[6];
  float* out = (float*)d_out;

  char* ws = (char*)d_ws;
  size_t off = 0;
  auto take = [&](size_t bytes) -> char* {
    char* p = ws + off;
    off += (bytes + 255) & ~(size_t)255;
    return p;
  };
  char* region0 = take((size_t)2 * M_ * NINP_ * 2);        // 72.1MB: Xh|Xl, later cur2
  u16* Xh  = (u16*)region0;
  u16* Xl  = (u16*)(region0 + (size_t)M_ * NINP_ * 2);
  float* cur2 = (float*)region0;                           // alias (after gemm0)
  char* region1 = take((size_t)M_ * H_ * 4);               // 52.4MB: cur1, later S2
  float* cur1 = (float*)region1;
  u16* S2 = (u16*)region1;                                 // alias (after scan1)
  u16* W0h = (u16*)take((size_t)H_ * NINP_ * 2);
  u16* W0l = (u16*)take((size_t)H_ * NINP_ * 2);
  u32* W1q = (u32*)take((size_t)H_ * KBIG_ * 4);           // interleaved hi/lo
  u16* Woh = (u16*)take((size_t)NOUTP_ * KBIG_ * 2);
  u16* Wol = (u16*)take((size_t)NOUTP_ * KBIG_ * 2);
  float* curo = (float*)take((size_t)M_ * NOUTP_ * 4);
  u32* S1q = (u32*)take((size_t)PLANES_ * B_ * H_ * 4);    // duplicated spike pairs

  // zero S1 history planes [0,40)
  hipMemsetAsync(S1q, 0, (size_t)40 * B_ * H_ * 4, stream);

  k_split_x<<<dim3(11, M_), 64, 0, stream>>>(in, Xh, Xl);
  k_split_w0<<<dim3(11, H_), 64, 0, stream>>>(W0, W0h, W0l);
  k_permsplit_w1q<<<dim3(80, H_), 64, 0, stream>>>(W1, W1q);
  k_permsplit_wo<<<dim3(80, NOUTP_), 64, 0, stream>>>(Wo, Woh, Wol);

  k_gemm0<<<dim3(4, 200), 256, 0, stream>>>(Xh, Xl, W0h, W0l, cur1);
  k_scan1<<<dim3(512), 256, 0, stream>>>(cur1, tau1, S1q);
  // cur1 dead; zero S2 history planes [0,40) in its place
  hipMemsetAsync(S2, 0, (size_t)40 * B_ * H_ * 2, stream);
  // Xh/Xl dead; cur2 overwrites region0
  k_gemm8_spk<<<dim3(2, 100), 512, 0, stream>>>((const u16*)S1q, (const u16*)W1q, cur2);
  k_scan2<<<dim3(512), 256, 0, stream>>>(cur2, tau2, S2);
  k_gemm_out<<<dim3(200), 256, 0, stream>>>(S2, Woh, Wol, curo);
  k_scan_o<<<dim3(4), 64, 0, stream>>>(curo, tauo, out);
}

// Round 6
// 798.361 us; speedup vs baseline: 1.1277x; 1.1277x over previous
//
#include <hip/hip_runtime.h>
#include <stdint.h>

#define THRESH_ 0.3f
constexpr int B_ = 256, WIN_ = 100, NIN_ = 700, NINP_ = 704, H_ = 512;
constexpr int NOUT_ = 20, NOUTP_ = 32, ND_ = 10, KBIG_ = 5120, M_ = 25600;
constexpr int PLANES_ = 140;   // 40 zero-history + 100
constexpr int KT_SPK = KBIG_ / 32;  // 160 K-tiles of 32 real k

typedef unsigned short u16;
typedef unsigned int u32;
typedef unsigned short u16x8 __attribute__((ext_vector_type(8)));
typedef float f32x4 __attribute__((ext_vector_type(4)));

// ---- fp16 RNE split ----
__device__ __forceinline__ u16 f2h(float f) {
  _Float16 h = (_Float16)f;           // RNE
  union { _Float16 h; u16 u; } v; v.h = h;
  return v.u;
}
__device__ __forceinline__ float h2f(u16 u) {
  union { u16 u; _Float16 h; } v; v.u = u;
  return (float)v.h;
}

__device__ __forceinline__ void mfma_h(f32x4& acc, u16x8 a, u16x8 b) {
  asm volatile("v_mfma_f32_16x16x32_f16 %0, %1, %2, %0" : "+v"(acc) : "v"(a), "v"(b));
}
__device__ __forceinline__ void gload16(const void* g, void* l) {
  __builtin_amdgcn_global_load_lds(
      (const __attribute__((address_space(1))) unsigned int*)g,
      (__attribute__((address_space(3))) unsigned int*)l, 16, 0, 0);
}

// ---------------- weight / input prep ----------------

__global__ void k_split_x(const float* __restrict__ in, u16* __restrict__ xh, u16* __restrict__ xl) {
  int k = blockIdx.x * 64 + threadIdx.x;   // [0,704)
  int r = blockIdx.y;                      // r = t*256 + b
  int t = r >> 8, b = r & 255;
  float v = (k < NIN_) ? in[(b * WIN_ + t) * NIN_ + k] : 0.f;
  u16 h = f2h(v);
  u16 lo = f2h(v - h2f(h));
  xh[r * NINP_ + k] = h;
  xl[r * NINP_ + k] = lo;
}

__global__ void k_split_w0(const float* __restrict__ w, u16* __restrict__ wh, u16* __restrict__ wl) {
  int k = blockIdx.x * 64 + threadIdx.x;   // [0,704)
  int j = blockIdx.y;                      // [0,512)
  float v = (k < NIN_) ? w[j * NIN_ + k] * 256.0f : 0.f;  // scale keeps low limb normal
  u16 h = f2h(v);
  u16 lo = f2h(v - h2f(h));
  wh[j * NINP_ + k] = h;
  wl[j * NINP_ + k] = lo;
}

// permute K: k' = d*512 + h  <-  reference col h*10 + d; 2-limb fp16, scaled x256
__global__ void k_permsplit_w1(const float* __restrict__ w, u16* __restrict__ wh, u16* __restrict__ wl) {
  int k = blockIdx.x * 64 + threadIdx.x;   // [0,5120)
  int j = blockIdx.y;                      // [0,512)
  int d = k >> 9, h = k & 511;
  float v = w[j * KBIG_ + h * ND_ + d] * 256.0f;
  u16 a = f2h(v);
  u16 b = f2h(v - h2f(a));
  wh[j * KBIG_ + k] = a;
  wl[j * KBIG_ + k] = b;
}

__global__ void k_permsplit_wo(const float* __restrict__ w, u16* __restrict__ wh, u16* __restrict__ wl) {
  int k = blockIdx.x * 64 + threadIdx.x;   // [0,5120)
  int j = blockIdx.y;                      // [0,32)
  int d = k >> 9, h = k & 511;
  float v = (j < NOUT_) ? w[j * KBIG_ + h * ND_ + d] * 256.0f : 0.f;
  u16 a = f2h(v);
  u16 b = f2h(v - h2f(a));
  wh[j * KBIG_ + k] = a;
  wl[j * KBIG_ + k] = b;
}

// ---------------- GEMM 0: cur1 = X @ W0^T  (fp16 2x2 split, 4 terms, BK=32) ----------------

__global__ __launch_bounds__(256) void k_gemm0(const u16* __restrict__ Xh, const u16* __restrict__ Xl,
                                               const u16* __restrict__ Wh, const u16* __restrict__ Wl,
                                               float* __restrict__ out) {
  __shared__ alignas(16) u16 lAh[128 * 32], lAl[128 * 32], lBh[128 * 32], lBl[128 * 32];
  const int tid = threadIdx.x, lane = tid & 63, wid = tid >> 6;
  const int m0 = blockIdx.y * 128, n0 = blockIdx.x * 128;
  const int wr = wid >> 1, wc = wid & 1;
  const int srow = lane >> 2;
  const int sk = 8 * ((lane & 3) ^ ((lane >> 3) & 3));  // source-side XOR swizzle (16B units)
  const int fr = lane & 15, kb = lane >> 4;
  int aoff[4], boff[4];
#pragma unroll
  for (int f = 0; f < 4; f++) {
    int row = wr * 64 + f * 16 + fr;
    aoff[f] = row * 32 + (kb ^ ((row >> 1) & 3)) * 8;
    int col = wc * 64 + f * 16 + fr;
    boff[f] = col * 32 + (kb ^ ((col >> 1) & 3)) * 8;
  }
  f32x4 acc[4][4] = {};
#pragma unroll 1
  for (int kk = 0; kk < NINP_ / 32; kk++) {
    const int k0 = kk * 32;
#pragma unroll
    for (int i = 0; i < 2; i++) {
      int c = wid + 4 * i;
      int ga = (m0 + c * 16 + srow) * NINP_ + k0 + sk;
      gload16(Xh + ga, &lAh[c * 512]);
      gload16(Xl + ga, &lAl[c * 512]);
      int gb = (n0 + c * 16 + srow) * NINP_ + k0 + sk;
      gload16(Wh + gb, &lBh[c * 512]);
      gload16(Wl + gb, &lBl[c * 512]);
    }
    asm volatile("s_waitcnt vmcnt(0)" ::: "memory");
    __syncthreads();
    u16x8 bh[4], bl[4];
#pragma unroll
    for (int j = 0; j < 4; j++) {
      bh[j] = *(const u16x8*)&lBh[boff[j]];
      bl[j] = *(const u16x8*)&lBl[boff[j]];
    }
#pragma unroll
    for (int i = 0; i < 4; i++) {
      u16x8 ah = *(const u16x8*)&lAh[aoff[i]];
      u16x8 al = *(const u16x8*)&lAl[aoff[i]];
#pragma unroll
      for (int j = 0; j < 4; j++) {
        mfma_h(acc[i][j], ah, bh[j]);
        mfma_h(acc[i][j], ah, bl[j]);
        mfma_h(acc[i][j], al, bh[j]);
        mfma_h(acc[i][j], al, bl[j]);
      }
    }
    __syncthreads();
  }
  asm volatile("s_nop 7\n\ts_nop 7" ::: "memory");
#pragma unroll
  for (int i = 0; i < 4; i++) {
    int row = m0 + wr * 64 + i * 16 + (lane >> 4) * 4;
#pragma unroll
    for (int j = 0; j < 4; j++) {
      int col = n0 + wc * 64 + j * 16 + fr;
#pragma unroll
      for (int r = 0; r < 4; r++)
        out[(row + r) * H_ + col] = acc[i][j][r] * (1.0f / 256.0f);  // undo W0 scale (exact)
    }
  }
}

// ---------------- GEMM spk (3-phase 256x256): cur2 = gather(S1) @ (W1h+W1l)^T ----------------
// A = plain spikes [140 planes][256][512] u16; B = W1h/W1l [512][5120]. Real K = 5120, BK = 32.
// LDS [dbuf][256][32] per operand (64B rows); slot swizzle g(row)=(row>>1)&3 (2-way = free).
// Phases/K-tile: ph0 {bh+av03, stage A'} ph1 {av47, stage Bh'} vmcnt(4)
//                ph2 {bl, stage Bl', 32 MFMA} vmcnt(2). Never drains to 0 mid-loop.

__global__ __launch_bounds__(512) void k_gemm8b_spk(const u16* __restrict__ S,
                                                    const u16* __restrict__ Wh,
                                                    const u16* __restrict__ Wl,
                                                    float* __restrict__ out) {
  __shared__ alignas(16) u16 sA[2][256][32];   // 32 KB
  __shared__ alignas(16) u16 sBh[2][256][32];  // 32 KB
  __shared__ alignas(16) u16 sBl[2][256][32];  // 32 KB
  const int tid = threadIdx.x;
  const int lane = tid & 63, wid = tid >> 6;   // 8 waves
  const int wm = wid >> 2, wn = wid & 3;       // 2 x 4 wave grid, per-wave 128x64
  const int fr = lane & 15, kb = lane >> 4;
  const int t = blockIdx.y;
  const int n0 = blockIdx.x * 256;

  const int rr4 = lane >> 2;                                  // staging row-in-chunk
  const int swz8 = ((lane & 3) ^ ((lane >> 3) & 3)) * 8;      // source slot: (l&3) ^ g(row)

  int aro[8], bro[4];
#pragma unroll
  for (int f = 0; f < 8; f++) {
    int row = wm * 128 + f * 16 + fr;
    aro[f] = row * 32 + (kb ^ ((fr >> 1) & 3)) * 8;           // g(row)=(row>>1)&3, base%16==0
  }
#pragma unroll
  for (int f = 0; f < 4; f++) {
    int row = wn * 64 + f * 16 + fr;
    bro[f] = row * 32 + (kb ^ ((fr >> 1) & 3)) * 8;
  }

  f32x4 acc[8][4] = {};

#define STAGE_A(buf, kt_) do { \
    int k0s = (kt_) * 32; \
    const u16* ba = S + ((size_t)((t + 4 * (k0s >> 9)) * 256)) * 512 + (k0s & 511) + swz8; \
    u16* da = &sA[(buf)][0][0]; \
    gload16(ba + (size_t)(wid * 16 + rr4) * 512, da + (wid * 16) * 32); \
    gload16(ba + (size_t)(128 + wid * 16 + rr4) * 512, da + (128 + wid * 16) * 32); \
  } while (0)
#define STAGE_B(buf, kt_, WSRC, DST) do { \
    int k0s = (kt_) * 32; \
    const u16* bb = (WSRC) + (size_t)(n0) * KBIG_ + k0s + swz8; \
    u16* db = &DST[(buf)][0][0]; \
    gload16(bb + (size_t)(wid * 16 + rr4) * KBIG_, db + (wid * 16) * 32); \
    gload16(bb + (size_t)(128 + wid * 16 + rr4) * KBIG_, db + (128 + wid * 16) * 32); \
  } while (0)

  // prologue: stage tile 0 fully, single full drain
  STAGE_A(0, 0);
  STAGE_B(0, 0, Wh, sBh);
  STAGE_B(0, 0, Wl, sBl);
  asm volatile("s_waitcnt vmcnt(0)" ::: "memory");
  __builtin_amdgcn_s_barrier();

#pragma unroll 1
  for (int kt = 0; kt < KT_SPK; ++kt) {
    const int c = kt & 1, nb = c ^ 1;
    const int ktn = (kt + 1 < KT_SPK) ? kt + 1 : kt;  // redundant last re-stage keeps ledger uniform
    const u16* pa = &sA[c][0][0];
    const u16* pbh = &sBh[c][0][0];
    const u16* pbl = &sBl[c][0][0];
    u16x8 av[8], bh[4], bl[4];
    // ---- ph0: hi-B frags + A(mh0); prefetch next A ----
#pragma unroll
    for (int f = 0; f < 4; f++) bh[f] = *(const u16x8*)(pbh + bro[f]);
#pragma unroll
    for (int f = 0; f < 4; f++) av[f] = *(const u16x8*)(pa + aro[f]);
    STAGE_A(nb, ktn);
    __builtin_amdgcn_s_barrier();
    __builtin_amdgcn_s_setprio(1);
#pragma unroll
    for (int mf = 0; mf < 4; mf++)
#pragma unroll
      for (int nf = 0; nf < 4; nf++) mfma_h(acc[mf][nf], av[mf], bh[nf]);
    __builtin_amdgcn_s_setprio(0);
    __builtin_amdgcn_s_barrier();
    // ---- ph1: A(mh1); prefetch next Bh ----
#pragma unroll
    for (int f = 4; f < 8; f++) av[f] = *(const u16x8*)(pa + aro[f]);
    STAGE_B(nb, ktn, Wh, sBh);
    __builtin_amdgcn_s_barrier();
    __builtin_amdgcn_s_setprio(1);
#pragma unroll
    for (int mf = 4; mf < 8; mf++)
#pragma unroll
      for (int nf = 0; nf < 4; nf++) mfma_h(acc[mf][nf], av[mf], bh[nf]);
    __builtin_amdgcn_s_setprio(0);
    asm volatile("s_waitcnt vmcnt(4)" ::: "memory");   // lands Bl(kt) (read next phase)
    __builtin_amdgcn_s_barrier();
    // ---- ph2: lo-B frags; prefetch next Bl; 32 MFMA ----
#pragma unroll
    for (int f = 0; f < 4; f++) bl[f] = *(const u16x8*)(pbl + bro[f]);
    STAGE_B(nb, ktn, Wl, sBl);
    __builtin_amdgcn_s_barrier();
    __builtin_amdgcn_s_setprio(1);
#pragma unroll
    for (int mf = 0; mf < 8; mf++)
#pragma unroll
      for (int nf = 0; nf < 4; nf++) mfma_h(acc[mf][nf], av[mf], bl[nf]);
    __builtin_amdgcn_s_setprio(0);
    asm volatile("s_waitcnt vmcnt(2)" ::: "memory");   // lands A(kt+1), Bh(kt+1)
    __builtin_amdgcn_s_barrier();
  }
#undef STAGE_A
#undef STAGE_B

  asm volatile("s_nop 7\n\ts_nop 7" ::: "memory");
#pragma unroll
  for (int i = 0; i < 8; i++) {
    int row = t * 256 + wm * 128 + i * 16 + kb * 4;
#pragma unroll
    for (int j = 0; j < 4; j++) {
      int col = n0 + wn * 64 + j * 16 + fr;
#pragma unroll
      for (int r = 0; r < 4; r++)
        out[(size_t)(row + r) * H_ + col] = acc[i][j][r] * (1.0f / 256.0f);  // undo W1 scale
    }
  }
}

// ---------------- GEMM out: curo = gather(S2) @ Wop^T  (N=32 padded, 2-limb, BK=32) ----------------

__global__ __launch_bounds__(256) void k_gemm_out(const u16* __restrict__ S, const u16* __restrict__ Wh,
                                                  const u16* __restrict__ Wl, float* __restrict__ out) {
  __shared__ alignas(16) u16 lA[128 * 32], lBh[32 * 32], lBl[32 * 32];
  const int tid = threadIdx.x, lane = tid & 63, wid = tid >> 6;
  const int mt = blockIdx.x;
  const int m0 = mt * 128;
  const int t = mt >> 1, brow0 = (mt & 1) * 128;
  const int srow = lane >> 2;
  const int sk = 8 * ((lane & 3) ^ ((lane >> 3) & 3));
  const int fr = lane & 15, kb = lane >> 4;
  int aoff[2], boff[2];
#pragma unroll
  for (int f = 0; f < 2; f++) {
    int row = wid * 32 + f * 16 + fr;
    aoff[f] = row * 32 + (kb ^ ((row >> 1) & 3)) * 8;
    int col = f * 16 + fr;
    boff[f] = col * 32 + (kb ^ ((col >> 1) & 3)) * 8;
  }
  f32x4 acc[2][2] = {};
#pragma unroll 1
  for (int kk = 0; kk < KBIG_ / 32; kk++) {
    const int k0 = kk * 32;
    const int d = k0 >> 9, h0 = k0 & 511;
    const int p = t + 4 * d;
#pragma unroll
    for (int i = 0; i < 2; i++) {
      int c = wid + 4 * i;
      gload16(S + ((size_t)(p * 256 + brow0 + c * 16 + srow) * 512 + h0 + sk), &lA[c * 512]);
    }
    {  // 4 B chunks (2 buffers x 2 halves) over 4 waves
      const u16* bs = (wid < 2) ? Wh : Wl;
      u16* bd = (wid < 2) ? (u16*)lBh : (u16*)lBl;
      int half = wid & 1;
      gload16(bs + (size_t)(half * 16 + srow) * KBIG_ + k0 + sk, &bd[half * 512]);
    }
    asm volatile("s_waitcnt vmcnt(0)" ::: "memory");
    __syncthreads();
    u16x8 bh[2], bl[2];
#pragma unroll
    for (int j = 0; j < 2; j++) {
      bh[j] = *(const u16x8*)&lBh[boff[j]];
      bl[j] = *(const u16x8*)&lBl[boff[j]];
    }
#pragma unroll
    for (int i = 0; i < 2; i++) {
      u16x8 a = *(const u16x8*)&lA[aoff[i]];
#pragma unroll
      for (int j = 0; j < 2; j++) {
        mfma_h(acc[i][j], a, bh[j]);
        mfma_h(acc[i][j], a, bl[j]);
      }
    }
    __syncthreads();
  }
  asm volatile("s_nop 7\n\ts_nop 7" ::: "memory");
#pragma unroll
  for (int i = 0; i < 2; i++) {
    int row = m0 + wid * 32 + i * 16 + (lane >> 4) * 4;
#pragma unroll
    for (int j = 0; j < 2; j++) {
      int col = j * 16 + fr;
#pragma unroll
      for (int r = 0; r < 4; r++)
        out[(row + r) * NOUTP_ + col] = acc[i][j][r] * (1.0f / 256.0f);  // undo Wo scale
    }
  }
}

// ---------------- elementwise LIF scans (strict fp32 rounding, no contraction) ----------------

__global__ void k_scan(const float* __restrict__ cur, const float* __restrict__ tau, u16* __restrict__ S) {
  int g = blockIdx.x * 256 + threadIdx.x;   // [0, 131072)
  int b = g >> 9, h = g & 511;
  float a = (float)(1.0 / (1.0 + exp(-(double)tau[h])));
  float mem = 0.f, s = 0.f;
#pragma unroll 1
  for (int t = 0; t < WIN_; t++) {
    float c = cur[(t * 256 + b) * 512 + h];
    mem = __fadd_rn(__fmul_rn(__fmul_rn(mem, a), __fsub_rn(1.f, s)), c);
    float x = __fsub_rn(mem, THRESH_);
    s = (x > 0.f) ? 1.f : 0.f;
    mem = (mem < THRESH_) ? mem : 0.f;
    S[((t + 40) * 256 + b) * 512 + h] = (x > 0.f) ? (u16)0x3C00 : (u16)0;  // fp16 1.0
  }
}

__global__ void k_scan_o(const float* __restrict__ curo, const float* __restrict__ tau, float* __restrict__ outp) {
  int b = blockIdx.x * 64 + threadIdx.x;
  if (b >= B_) return;
  float ao[NOUT_], mem[NOUT_], spk[NOUT_], osum[NOUT_], mot[NOUT_];
#pragma unroll
  for (int j = 0; j < NOUT_; j++) {
    ao[j] = (float)(1.0 / (1.0 + exp(-(double)tau[j])));
    mem[j] = 0.f; spk[j] = 0.f; osum[j] = 0.f; mot[j] = 0.f;
  }
#pragma unroll 1
  for (int t = 0; t < WIN_; t++) {
    const float4* rowp = (const float4*)&curo[(t * 256 + b) * NOUTP_];
    float4 v[5];
#pragma unroll
    for (int q = 0; q < 5; q++) v[q] = rowp[q];
    float cv[NOUT_];
#pragma unroll
    for (int q = 0; q < 5; q++) {
      cv[4 * q + 0] = v[q].x; cv[4 * q + 1] = v[q].y;
      cv[4 * q + 2] = v[q].z; cv[4 * q + 3] = v[q].w;
    }
#pragma unroll
    for (int j = 0; j < NOUT_; j++) {
      mem[j] = __fadd_rn(__fmul_rn(__fmul_rn(mem[j], ao[j]), __fsub_rn(1.f, spk[j])), cv[j]);
      float x = __fsub_rn(mem[j], THRESH_);
      spk[j] = (x > 0.f) ? 1.f : 0.f;
      mem[j] = (mem[j] < THRESH_) ? mem[j] : 0.f;
      osum[j] = __fadd_rn(osum[j], spk[j]);
    }
    float mx = -1e30f;
#pragma unroll
    for (int j = 0; j < NOUT_; j++) mx = fmaxf(mx, mem[j]);
    float se = 0.f, e[NOUT_];
#pragma unroll
    for (int j = 0; j < NOUT_; j++) { e[j] = expf(__fsub_rn(mem[j], mx)); se = __fadd_rn(se, e[j]); }
#pragma unroll
    for (int j = 0; j < NOUT_; j++) mot[j] = __fadd_rn(mot[j], __fdiv_rn(e[j], se));
  }
#pragma unroll
  for (int j = 0; j < NOUT_; j++) {
    outp[b * NOUT_ + j] = __fdiv_rn(osum[j], 100.0f);
    outp[B_ * NOUT_ + b * NOUT_ + j] = mot[j];
  }
}

// ---------------- launch ----------------
// Workspace aliasing (liveness-based, ~177MB < 214MB proven in R5):
//   region0 (72.1MB): Xh+Xl -> dead after k_gemm0 -> cur2 (52.4MB)
//   region1 (52.4MB): cur1  -> dead after scan1   -> S2   (36.7MB)

extern "C" void kernel_launch(void* const* d_in, const int* in_sizes, int n_in,
                              void* d_out, int out_size, void* d_ws, size_t ws_size,
                              hipStream_t stream) {
  const float* in   = (const float*)d_in[0];
  const float* W0   = (const float*)d_in[1];
  const float* W1   = (const float*)d_in[2];
  const float* Wo   = (const float*)d_in[3];
  const float* tau1 = (const float*)d_in[4];
  const float* tau2 = (const float*)d_in[5];
  const float* tauo = (const float*)d_in[6];
  float* out = (float*)d_out;

  char* ws = (char*)d_ws;
  size_t off = 0;
  auto take = [&](size_t bytes) -> char* {
    char* p = ws + off;
    off += (bytes + 255) & ~(size_t)255;
    return p;
  };
  char* region0 = take((size_t)2 * M_ * NINP_ * 2);        // Xh|Xl, later cur2
  u16* Xh  = (u16*)region0;
  u16* Xl  = (u16*)(region0 + (size_t)M_ * NINP_ * 2);
  float* cur2 = (float*)region0;                           // alias (after gemm0)
  char* region1 = take((size_t)M_ * H_ * 4);               // cur1, later S2
  float* cur1 = (float*)region1;
  u16* S2 = (u16*)region1;                                 // alias (after scan1)
  u16* W0h = (u16*)take((size_t)H_ * NINP_ * 2);
  u16* W0l = (u16*)take((size_t)H_ * NINP_ * 2);
  u16* W1h = (u16*)take((size_t)H_ * KBIG_ * 2);
  u16* W1l = (u16*)take((size_t)H_ * KBIG_ * 2);
  u16* Woh = (u16*)take((size_t)NOUTP_ * KBIG_ * 2);
  u16* Wol = (u16*)take((size_t)NOUTP_ * KBIG_ * 2);
  float* curo = (float*)take((size_t)M_ * NOUTP_ * 4);
  u16* S1 = (u16*)take((size_t)PLANES_ * B_ * H_ * 2);     // plain fp16 spikes

  // zero S1 history planes [0,40)
  hipMemsetAsync(S1, 0, (size_t)40 * B_ * H_ * 2, stream);

  k_split_x<<<dim3(11, M_), 64, 0, stream>>>(in, Xh, Xl);
  k_split_w0<<<dim3(11, H_), 64, 0, stream>>>(W0, W0h, W0l);
  k_permsplit_w1<<<dim3(80, H_), 64, 0, stream>>>(W1, W1h, W1l);
  k_permsplit_wo<<<dim3(80, NOUTP_), 64, 0, stream>>>(Wo, Woh, Wol);

  k_gemm0<<<dim3(4, 200), 256, 0, stream>>>(Xh, Xl, W0h, W0l, cur1);
  k_scan<<<dim3(512), 256, 0, stream>>>(cur1, tau1, S1);
  // cur1 dead; zero S2 history planes [0,40) in its place
  hipMemsetAsync(S2, 0, (size_t)40 * B_ * H_ * 2, stream);
  // Xh/Xl dead; cur2 overwrites region0
  k_gemm8b_spk<<<dim3(2, 100), 512, 0, stream>>>(S1, W1h, W1l, cur2);
  k_scan<<<dim3(512), 256, 0, stream>>>(cur2, tau2, S2);
  k_gemm_out<<<dim3(200), 256, 0, stream>>>(S2, Woh, Wol, curo);
  k_scan_o<<<dim3(4), 64, 0, stream>>>(curo, tauo, out);
}

// Round 7
// 798.207 us; speedup vs baseline: 1.1280x; 1.0002x over previous
//
#include <hip/hip_runtime.h>
#include <stdint.h>

#define THRESH_ 0.3f
constexpr int B_ = 256, WIN_ = 100, NIN_ = 700, NINP_ = 704, H_ = 512;
constexpr int NOUT_ = 20, NOUTP_ = 32, ND_ = 10, KBIG_ = 5120, M_ = 25600;
constexpr int PLANES_ = 140;   // 40 zero-history + 100
constexpr int KT_SPK = KBIG_ / 32;  // 160 K-tiles of 32 real k

typedef unsigned short u16;
typedef unsigned int u32;
typedef unsigned short u16x8 __attribute__((ext_vector_type(8)));
typedef float f32x4 __attribute__((ext_vector_type(4)));

// ---- fp16 RNE split ----
__device__ __forceinline__ u16 f2h(float f) {
  _Float16 h = (_Float16)f;           // RNE
  union { _Float16 h; u16 u; } v; v.h = h;
  return v.u;
}
__device__ __forceinline__ float h2f(u16 u) {
  union { u16 u; _Float16 h; } v; v.u = u;
  return (float)v.h;
}

__device__ __forceinline__ void mfma_h(f32x4& acc, u16x8 a, u16x8 b) {
  asm volatile("v_mfma_f32_16x16x32_f16 %0, %1, %2, %0" : "+v"(acc) : "v"(a), "v"(b));
}
__device__ __forceinline__ void gload16(const void* g, void* l) {
  __builtin_amdgcn_global_load_lds(
      (const __attribute__((address_space(1))) unsigned int*)g,
      (__attribute__((address_space(3))) unsigned int*)l, 16, 0, 0);
}

// ---------------- weight / input prep ----------------

__global__ void k_split_x(const float* __restrict__ in, u16* __restrict__ xh, u16* __restrict__ xl) {
  int k = blockIdx.x * 64 + threadIdx.x;   // [0,704)
  int r = blockIdx.y;                      // r = t*256 + b
  int t = r >> 8, b = r & 255;
  float v = (k < NIN_) ? in[(b * WIN_ + t) * NIN_ + k] : 0.f;
  u16 h = f2h(v);
  u16 lo = f2h(v - h2f(h));
  xh[r * NINP_ + k] = h;
  xl[r * NINP_ + k] = lo;
}

__global__ void k_split_w0(const float* __restrict__ w, u16* __restrict__ wh, u16* __restrict__ wl) {
  int k = blockIdx.x * 64 + threadIdx.x;   // [0,704)
  int j = blockIdx.y;                      // [0,512)
  float v = (k < NIN_) ? w[j * NIN_ + k] * 256.0f : 0.f;  // scale keeps low limb normal
  u16 h = f2h(v);
  u16 lo = f2h(v - h2f(h));
  wh[j * NINP_ + k] = h;
  wl[j * NINP_ + k] = lo;
}

// permute K: k' = d*512 + h  <-  reference col h*10 + d; 2-limb fp16, scaled x256
__global__ void k_permsplit_w1(const float* __restrict__ w, u16* __restrict__ wh, u16* __restrict__ wl) {
  int k = blockIdx.x * 64 + threadIdx.x;   // [0,5120)
  int j = blockIdx.y;                      // [0,512)
  int d = k >> 9, h = k & 511;
  float v = w[j * KBIG_ + h * ND_ + d] * 256.0f;
  u16 a = f2h(v);
  u16 b = f2h(v - h2f(a));
  wh[j * KBIG_ + k] = a;
  wl[j * KBIG_ + k] = b;
}

__global__ void k_permsplit_wo(const float* __restrict__ w, u16* __restrict__ wh, u16* __restrict__ wl) {
  int k = blockIdx.x * 64 + threadIdx.x;   // [0,5120)
  int j = blockIdx.y;                      // [0,32)
  int d = k >> 9, h = k & 511;
  float v = (j < NOUT_) ? w[j * KBIG_ + h * ND_ + d] * 256.0f : 0.f;
  u16 a = f2h(v);
  u16 b = f2h(v - h2f(a));
  wh[j * KBIG_ + k] = a;
  wl[j * KBIG_ + k] = b;
}

// ---------------- GEMM 0: cur1 = X @ W0^T  (fp16 2x2 split, 4 terms, BK=32) ----------------

__global__ __launch_bounds__(256) void k_gemm0(const u16* __restrict__ Xh, const u16* __restrict__ Xl,
                                               const u16* __restrict__ Wh, const u16* __restrict__ Wl,
                                               float* __restrict__ out) {
  __shared__ alignas(16) u16 lAh[128 * 32], lAl[128 * 32], lBh[128 * 32], lBl[128 * 32];
  const int tid = threadIdx.x, lane = tid & 63, wid = tid >> 6;
  const int m0 = blockIdx.y * 128, n0 = blockIdx.x * 128;
  const int wr = wid >> 1, wc = wid & 1;
  const int srow = lane >> 2;
  const int sk = 8 * ((lane & 3) ^ ((lane >> 3) & 3));  // source-side XOR swizzle (16B units)
  const int fr = lane & 15, kb = lane >> 4;
  int aoff[4], boff[4];
#pragma unroll
  for (int f = 0; f < 4; f++) {
    int row = wr * 64 + f * 16 + fr;
    aoff[f] = row * 32 + (kb ^ ((row >> 1) & 3)) * 8;
    int col = wc * 64 + f * 16 + fr;
    boff[f] = col * 32 + (kb ^ ((col >> 1) & 3)) * 8;
  }
  f32x4 acc[4][4] = {};
#pragma unroll 1
  for (int kk = 0; kk < NINP_ / 32; kk++) {
    const int k0 = kk * 32;
#pragma unroll
    for (int i = 0; i < 2; i++) {
      int c = wid + 4 * i;
      int ga = (m0 + c * 16 + srow) * NINP_ + k0 + sk;
      gload16(Xh + ga, &lAh[c * 512]);
      gload16(Xl + ga, &lAl[c * 512]);
      int gb = (n0 + c * 16 + srow) * NINP_ + k0 + sk;
      gload16(Wh + gb, &lBh[c * 512]);
      gload16(Wl + gb, &lBl[c * 512]);
    }
    asm volatile("s_waitcnt vmcnt(0)" ::: "memory");
    __syncthreads();
    u16x8 bh[4], bl[4];
#pragma unroll
    for (int j = 0; j < 4; j++) {
      bh[j] = *(const u16x8*)&lBh[boff[j]];
      bl[j] = *(const u16x8*)&lBl[boff[j]];
    }
#pragma unroll
    for (int i = 0; i < 4; i++) {
      u16x8 ah = *(const u16x8*)&lAh[aoff[i]];
      u16x8 al = *(const u16x8*)&lAl[aoff[i]];
#pragma unroll
      for (int j = 0; j < 4; j++) {
        mfma_h(acc[i][j], ah, bh[j]);
        mfma_h(acc[i][j], ah, bl[j]);
        mfma_h(acc[i][j], al, bh[j]);
        mfma_h(acc[i][j], al, bl[j]);
      }
    }
    __syncthreads();
  }
  asm volatile("s_nop 7\n\ts_nop 7" ::: "memory");
#pragma unroll
  for (int i = 0; i < 4; i++) {
    int row = m0 + wr * 64 + i * 16 + (lane >> 4) * 4;
#pragma unroll
    for (int j = 0; j < 4; j++) {
      int col = n0 + wc * 64 + j * 16 + fr;
#pragma unroll
      for (int r = 0; r < 4; r++)
        out[(row + r) * H_ + col] = acc[i][j][r] * (1.0f / 256.0f);  // undo W0 scale (exact)
    }
  }
}

// ---------------- GEMM spk (3-phase, triple-buffered): cur2 = gather(S1) @ (W1h+W1l)^T ----------------
// A = plain spikes [140 planes][256][512] u16; B = W1h/W1l [512][5120]. Real K = 5120, BK = 32.
// LDS [3][256][32] per operand (64B rows); slot swizzle g(row)=(row>>1)&3 (2-way = free, R6-verified 0).
// Prefetch distance = 2 K-tiles: phases of kt issue units for kt+2; single vmcnt(6) at end of
// ph2 drains tile kt+1's 6 loads (issued ~6 phases earlier) -> covers HBM stream latency of A.

__global__ __launch_bounds__(512) void k_gemm3p_spk(const u16* __restrict__ S,
                                                    const u16* __restrict__ Wh,
                                                    const u16* __restrict__ Wl,
                                                    float* __restrict__ out) {
  __shared__ alignas(16) u16 sA[3][256][32];   // 48 KB
  __shared__ alignas(16) u16 sBh[3][256][32];  // 48 KB
  __shared__ alignas(16) u16 sBl[3][256][32];  // 48 KB
  const int tid = threadIdx.x;
  const int lane = tid & 63, wid = tid >> 6;   // 8 waves
  const int wm = wid >> 2, wn = wid & 3;       // 2 x 4 wave grid, per-wave 128x64
  const int fr = lane & 15, kb = lane >> 4;
  const int t = blockIdx.y;
  const int n0 = blockIdx.x * 256;

  const int rr4 = lane >> 2;                                  // staging row-in-chunk
  const int swz8 = ((lane & 3) ^ ((lane >> 3) & 3)) * 8;      // source slot: (l&3) ^ g(row)

  int aro[8], bro[4];
#pragma unroll
  for (int f = 0; f < 8; f++) {
    int row = wm * 128 + f * 16 + fr;
    aro[f] = row * 32 + (kb ^ ((fr >> 1) & 3)) * 8;           // g(row)=(row>>1)&3
  }
#pragma unroll
  for (int f = 0; f < 4; f++) {
    int row = wn * 64 + f * 16 + fr;
    bro[f] = row * 32 + (kb ^ ((fr >> 1) & 3)) * 8;
  }

  f32x4 acc[8][4] = {};

#define STAGE_A(buf, kt_) do { \
    int k0s = (kt_) * 32; \
    const u16* ba = S + ((size_t)((t + 4 * (k0s >> 9)) * 256)) * 512 + (k0s & 511) + swz8; \
    u16* da = &sA[(buf)][0][0]; \
    gload16(ba + (size_t)(wid * 16 + rr4) * 512, da + (wid * 16) * 32); \
    gload16(ba + (size_t)(128 + wid * 16 + rr4) * 512, da + (128 + wid * 16) * 32); \
  } while (0)
#define STAGE_B(buf, kt_, WSRC, DST) do { \
    int k0s = (kt_) * 32; \
    const u16* bb = (WSRC) + (size_t)(n0) * KBIG_ + k0s + swz8; \
    u16* db = &DST[(buf)][0][0]; \
    gload16(bb + (size_t)(wid * 16 + rr4) * KBIG_, db + (wid * 16) * 32); \
    gload16(bb + (size_t)(128 + wid * 16 + rr4) * KBIG_, db + (128 + wid * 16) * 32); \
  } while (0)

  // prologue: stage tiles 0 and 1 fully (12 loads); vmcnt(6) -> tile 0 landed
  STAGE_A(0, 0);
  STAGE_B(0, 0, Wh, sBh);
  STAGE_B(0, 0, Wl, sBl);
  STAGE_A(1, 1);
  STAGE_B(1, 1, Wh, sBh);
  STAGE_B(1, 1, Wl, sBl);
  asm volatile("s_waitcnt vmcnt(6)" ::: "memory");
  __builtin_amdgcn_s_barrier();

  int c = 0, w = 2;  // read buf, write buf (w = (c+2)%3)
#pragma unroll 1
  for (int kt = 0; kt < KT_SPK; ++kt) {
    const int ktn = (kt + 2 < KT_SPK) ? kt + 2 : KT_SPK - 1;  // redundant tail re-stage keeps ledger uniform
    const u16* pa = &sA[c][0][0];
    const u16* pbh = &sBh[c][0][0];
    const u16* pbl = &sBl[c][0][0];
    u16x8 av[8], bh[4], bl[4];
    // ---- ph0: hi-B frags + A(mh0); issue A(kt+2) ----
#pragma unroll
    for (int f = 0; f < 4; f++) bh[f] = *(const u16x8*)(pbh + bro[f]);
#pragma unroll
    for (int f = 0; f < 4; f++) av[f] = *(const u16x8*)(pa + aro[f]);
    STAGE_A(w, ktn);
    __builtin_amdgcn_s_barrier();
    __builtin_amdgcn_s_setprio(1);
#pragma unroll
    for (int mf = 0; mf < 4; mf++)
#pragma unroll
      for (int nf = 0; nf < 4; nf++) mfma_h(acc[mf][nf], av[mf], bh[nf]);
    __builtin_amdgcn_s_setprio(0);
    __builtin_amdgcn_s_barrier();
    // ---- ph1: A(mh1); issue Bh(kt+2) ----
#pragma unroll
    for (int f = 4; f < 8; f++) av[f] = *(const u16x8*)(pa + aro[f]);
    STAGE_B(w, ktn, Wh, sBh);
    __builtin_amdgcn_s_barrier();
    __builtin_amdgcn_s_setprio(1);
#pragma unroll
    for (int mf = 4; mf < 8; mf++)
#pragma unroll
      for (int nf = 0; nf < 4; nf++) mfma_h(acc[mf][nf], av[mf], bh[nf]);
    __builtin_amdgcn_s_setprio(0);
    __builtin_amdgcn_s_barrier();
    // ---- ph2: lo-B frags; issue Bl(kt+2); 32 MFMA; drain tile kt+1's 6 loads ----
#pragma unroll
    for (int f = 0; f < 4; f++) bl[f] = *(const u16x8*)(pbl + bro[f]);
    STAGE_B(w, ktn, Wl, sBl);
    __builtin_amdgcn_s_barrier();
    __builtin_amdgcn_s_setprio(1);
#pragma unroll
    for (int mf = 0; mf < 8; mf++)
#pragma unroll
      for (int nf = 0; nf < 4; nf++) mfma_h(acc[mf][nf], av[mf], bl[nf]);
    __builtin_amdgcn_s_setprio(0);
    asm volatile("s_waitcnt vmcnt(6)" ::: "memory");
    __builtin_amdgcn_s_barrier();
    c = (c == 2) ? 0 : c + 1;
    w = (w == 2) ? 0 : w + 1;
  }
#undef STAGE_A
#undef STAGE_B

  asm volatile("s_nop 7\n\ts_nop 7" ::: "memory");
#pragma unroll
  for (int i = 0; i < 8; i++) {
    int row = t * 256 + wm * 128 + i * 16 + kb * 4;
#pragma unroll
    for (int j = 0; j < 4; j++) {
      int col = n0 + wn * 64 + j * 16 + fr;
#pragma unroll
      for (int r = 0; r < 4; r++)
        out[(size_t)(row + r) * H_ + col] = acc[i][j][r] * (1.0f / 256.0f);  // undo W1 scale
    }
  }
}

// ---------------- GEMM out: curo = gather(S2) @ Wop^T  (N=32 padded, 2-limb, BK=32) ----------------

__global__ __launch_bounds__(256) void k_gemm_out(const u16* __restrict__ S, const u16* __restrict__ Wh,
                                                  const u16* __restrict__ Wl, float* __restrict__ out) {
  __shared__ alignas(16) u16 lA[128 * 32], lBh[32 * 32], lBl[32 * 32];
  const int tid = threadIdx.x, lane = tid & 63, wid = tid >> 6;
  const int mt = blockIdx.x;
  const int m0 = mt * 128;
  const int t = mt >> 1, brow0 = (mt & 1) * 128;
  const int srow = lane >> 2;
  const int sk = 8 * ((lane & 3) ^ ((lane >> 3) & 3));
  const int fr = lane & 15, kb = lane >> 4;
  int aoff[2], boff[2];
#pragma unroll
  for (int f = 0; f < 2; f++) {
    int row = wid * 32 + f * 16 + fr;
    aoff[f] = row * 32 + (kb ^ ((row >> 1) & 3)) * 8;
    int col = f * 16 + fr;
    boff[f] = col * 32 + (kb ^ ((col >> 1) & 3)) * 8;
  }
  f32x4 acc[2][2] = {};
#pragma unroll 1
  for (int kk = 0; kk < KBIG_ / 32; kk++) {
    const int k0 = kk * 32;
    const int d = k0 >> 9, h0 = k0 & 511;
    const int p = t + 4 * d;
#pragma unroll
    for (int i = 0; i < 2; i++) {
      int c = wid + 4 * i;
      gload16(S + ((size_t)(p * 256 + brow0 + c * 16 + srow) * 512 + h0 + sk), &lA[c * 512]);
    }
    {  // 4 B chunks (2 buffers x 2 halves) over 4 waves
      const u16* bs = (wid < 2) ? Wh : Wl;
      u16* bd = (wid < 2) ? (u16*)lBh : (u16*)lBl;
      int half = wid & 1;
      gload16(bs + (size_t)(half * 16 + srow) * KBIG_ + k0 + sk, &bd[half * 512]);
    }
    asm volatile("s_waitcnt vmcnt(0)" ::: "memory");
    __syncthreads();
    u16x8 bh[2], bl[2];
#pragma unroll
    for (int j = 0; j < 2; j++) {
      bh[j] = *(const u16x8*)&lBh[boff[j]];
      bl[j] = *(const u16x8*)&lBl[boff[j]];
    }
#pragma unroll
    for (int i = 0; i < 2; i++) {
      u16x8 a = *(const u16x8*)&lA[aoff[i]];
#pragma unroll
      for (int j = 0; j < 2; j++) {
        mfma_h(acc[i][j], a, bh[j]);
        mfma_h(acc[i][j], a, bl[j]);
      }
    }
    __syncthreads();
  }
  asm volatile("s_nop 7\n\ts_nop 7" ::: "memory");
#pragma unroll
  for (int i = 0; i < 2; i++) {
    int row = m0 + wid * 32 + i * 16 + (lane >> 4) * 4;
#pragma unroll
    for (int j = 0; j < 2; j++) {
      int col = j * 16 + fr;
#pragma unroll
      for (int r = 0; r < 4; r++)
        out[(row + r) * NOUTP_ + col] = acc[i][j][r] * (1.0f / 256.0f);  // undo Wo scale
    }
  }
}

// ---------------- elementwise LIF scans (strict fp32 rounding, no contraction) ----------------

__global__ void k_scan(const float* __restrict__ cur, const float* __restrict__ tau, u16* __restrict__ S) {
  int g = blockIdx.x * 256 + threadIdx.x;   // [0, 131072)
  int b = g >> 9, h = g & 511;
  float a = (float)(1.0 / (1.0 + exp(-(double)tau[h])));
  float mem = 0.f, s = 0.f;
#pragma unroll 1
  for (int t = 0; t < WIN_; t++) {
    float c = cur[(t * 256 + b) * 512 + h];
    mem = __fadd_rn(__fmul_rn(__fmul_rn(mem, a), __fsub_rn(1.f, s)), c);
    float x = __fsub_rn(mem, THRESH_);
    s = (x > 0.f) ? 1.f : 0.f;
    mem = (mem < THRESH_) ? mem : 0.f;
    S[((t + 40) * 256 + b) * 512 + h] = (x > 0.f) ? (u16)0x3C00 : (u16)0;  // fp16 1.0
  }
}

__global__ void k_scan_o(const float* __restrict__ curo, const float* __restrict__ tau, float* __restrict__ outp) {
  int b = blockIdx.x * 64 + threadIdx.x;
  if (b >= B_) return;
  float ao[NOUT_], mem[NOUT_], spk[NOUT_], osum[NOUT_], mot[NOUT_];
#pragma unroll
  for (int j = 0; j < NOUT_; j++) {
    ao[j] = (float)(1.0 / (1.0 + exp(-(double)tau[j])));
    mem[j] = 0.f; spk[j] = 0.f; osum[j] = 0.f; mot[j] = 0.f;
  }
#pragma unroll 1
  for (int t = 0; t < WIN_; t++) {
    const float4* rowp = (const float4*)&curo[(t * 256 + b) * NOUTP_];
    float4 v[5];
#pragma unroll
    for (int q = 0; q < 5; q++) v[q] = rowp[q];
    float cv[NOUT_];
#pragma unroll
    for (int q = 0; q < 5; q++) {
      cv[4 * q + 0] = v[q].x; cv[4 * q + 1] = v[q].y;
      cv[4 * q + 2] = v[q].z; cv[4 * q + 3] = v[q].w;
    }
#pragma unroll
    for (int j = 0; j < NOUT_; j++) {
      mem[j] = __fadd_rn(__fmul_rn(__fmul_rn(mem[j], ao[j]), __fsub_rn(1.f, spk[j])), cv[j]);
      float x = __fsub_rn(mem[j], THRESH_);
      spk[j] = (x > 0.f) ? 1.f : 0.f;
      mem[j] = (mem[j] < THRESH_) ? mem[j] : 0.f;
      osum[j] = __fadd_rn(osum[j], spk[j]);
    }
    float mx = -1e30f;
#pragma unroll
    for (int j = 0; j < NOUT_; j++) mx = fmaxf(mx, mem[j]);
    float se = 0.f, e[NOUT_];
#pragma unroll
    for (int j = 0; j < NOUT_; j++) { e[j] = expf(__fsub_rn(mem[j], mx)); se = __fadd_rn(se, e[j]); }
#pragma unroll
    for (int j = 0; j < NOUT_; j++) mot[j] = __fadd_rn(mot[j], __fdiv_rn(e[j], se));
  }
#pragma unroll
  for (int j = 0; j < NOUT_; j++) {
    outp[b * NOUT_ + j] = __fdiv_rn(osum[j], 100.0f);
    outp[B_ * NOUT_ + b * NOUT_ + j] = mot[j];
  }
}

// ---------------- launch ----------------
// Workspace aliasing (liveness-based, ~177MB < 214MB proven in R5):
//   region0 (72.1MB): Xh+Xl -> dead after k_gemm0 -> cur2 (52.4MB)
//   region1 (52.4MB): cur1  -> dead after scan1   -> S2   (36.7MB)

extern "C" void kernel_launch(void* const* d_in, const int* in_sizes, int n_in,
                              void* d_out, int out_size, void* d_ws, size_t ws_size,
                              hipStream_t stream) {
  const float* in   = (const float*)d_in[0];
  const float* W0   = (const float*)d_in[1];
  const float* W1   = (const float*)d_in[2];
  const float* Wo   = (const float*)d_in[3];
  const float* tau1 = (const float*)d_in[4];
  const float* tau2 = (const float*)d_in[5];
  const float* tauo = (const float*)d_in[6];
  float* out = (float*)d_out;

  char* ws = (char*)d_ws;
  size_t off = 0;
  auto take = [&](size_t bytes) -> char* {
    char* p = ws + off;
    off += (bytes + 255) & ~(size_t)255;
    return p;
  };
  char* region0 = take((size_t)2 * M_ * NINP_ * 2);        // Xh|Xl, later cur2
  u16* Xh  = (u16*)region0;
  u16* Xl  = (u16*)(region0 + (size_t)M_ * NINP_ * 2);
  float* cur2 = (float*)region0;                           // alias (after gemm0)
  char* region1 = take((size_t)M_ * H_ * 4);               // cur1, later S2
  float* cur1 = (float*)region1;
  u16* S2 = (u16*)region1;                                 // alias (after scan1)
  u16* W0h = (u16*)take((size_t)H_ * NINP_ * 2);
  u16* W0l = (u16*)take((size_t)H_ * NINP_ * 2);
  u16* W1h = (u16*)take((size_t)H_ * KBIG_ * 2);
  u16* W1l = (u16*)take((size_t)H_ * KBIG_ * 2);
  u16* Woh = (u16*)take((size_t)NOUTP_ * KBIG_ * 2);
  u16* Wol = (u16*)take((size_t)NOUTP_ * KBIG_ * 2);
  float* curo = (float*)take((size_t)M_ * NOUTP_ * 4);
  u16* S1 = (u16*)take((size_t)PLANES_ * B_ * H_ * 2);     // plain fp16 spikes

  // zero S1 history planes [0,40)
  hipMemsetAsync(S1, 0, (size_t)40 * B_ * H_ * 2, stream);

  k_split_x<<<dim3(11, M_), 64, 0, stream>>>(in, Xh, Xl);
  k_split_w0<<<dim3(11, H_), 64, 0, stream>>>(W0, W0h, W0l);
  k_permsplit_w1<<<dim3(80, H_), 64, 0, stream>>>(W1, W1h, W1l);
  k_permsplit_wo<<<dim3(80, NOUTP_), 64, 0, stream>>>(Wo, Woh, Wol);

  k_gemm0<<<dim3(4, 200), 256, 0, stream>>>(Xh, Xl, W0h, W0l, cur1);
  k_scan<<<dim3(512), 256, 0, stream>>>(cur1, tau1, S1);
  // cur1 dead; zero S2 history planes [0,40) in its place
  hipMemsetAsync(S2, 0, (size_t)40 * B_ * H_ * 2, stream);
  // Xh/Xl dead; cur2 overwrites region0
  k_gemm3p_spk<<<dim3(2, 100), 512, 0, stream>>>(S1, W1h, W1l, cur2);
  k_scan<<<dim3(512), 256, 0, stream>>>(cur2, tau2, S2);
  k_gemm_out<<<dim3(200), 256, 0, stream>>>(S2, Woh, Wol, curo);
  k_scan_o<<<dim3(4), 64, 0, stream>>>(curo, tauo, out);
}

// Round 8
// 663.277 us; speedup vs baseline: 1.3574x; 1.2034x over previous
//
#include <hip/hip_runtime.h>
#include <stdint.h>

#define THRESH_ 0.3f
constexpr int B_ = 256, WIN_ = 100, NIN_ = 700, NINP_ = 704, H_ = 512;
constexpr int NOUT_ = 20, NOUTP_ = 32, ND_ = 10, KBIG_ = 5120, M_ = 25600;
constexpr int PLANES_ = 140;   // 40 zero-history + 100

typedef unsigned short u16;
typedef unsigned int u32;
typedef unsigned short u16x8 __attribute__((ext_vector_type(8)));
typedef float f32x4 __attribute__((ext_vector_type(4)));

// ---- fp16 RNE split ----
__device__ __forceinline__ u16 f2h(float f) {
  _Float16 h = (_Float16)f;           // RNE
  union { _Float16 h; u16 u; } v; v.h = h;
  return v.u;
}
__device__ __forceinline__ float h2f(u16 u) {
  union { u16 u; _Float16 h; } v; v.u = u;
  return (float)v.h;
}

__device__ __forceinline__ void mfma_h(f32x4& acc, u16x8 a, u16x8 b) {
  asm volatile("v_mfma_f32_16x16x32_f16 %0, %1, %2, %0" : "+v"(acc) : "v"(a), "v"(b));
}
__device__ __forceinline__ void gload16(const void* g, void* l) {
  __builtin_amdgcn_global_load_lds(
      (const __attribute__((address_space(1))) unsigned int*)g,
      (__attribute__((address_space(3))) unsigned int*)l, 16, 0, 0);
}

// ---------------- weight / input prep (256-thread blocks) ----------------

__global__ __launch_bounds__(256) void k_split_x(const float* __restrict__ in,
                                                 u16* __restrict__ xh, u16* __restrict__ xl) {
  int r = blockIdx.x;                      // [0,25600), r = t*256 + b
  int t = r >> 8, b = r & 255;
  const float* src = in + (size_t)(b * WIN_ + t) * NIN_;
#pragma unroll
  for (int i = 0; i < 3; i++) {
    int k = threadIdx.x + 256 * i;
    if (k < NINP_) {
      float v = (k < NIN_) ? src[k] : 0.f;
      u16 h = f2h(v);
      u16 lo = f2h(v - h2f(h));
      xh[(size_t)r * NINP_ + k] = h;
      xl[(size_t)r * NINP_ + k] = lo;
    }
  }
}

__global__ __launch_bounds__(256) void k_split_w0(const float* __restrict__ w,
                                                  u16* __restrict__ wh, u16* __restrict__ wl) {
  int j = blockIdx.x;                      // [0,512)
#pragma unroll
  for (int i = 0; i < 3; i++) {
    int k = threadIdx.x + 256 * i;
    if (k < NINP_) {
      float v = (k < NIN_) ? w[j * NIN_ + k] * 256.0f : 0.f;  // scale keeps low limb normal
      u16 h = f2h(v);
      u16 lo = f2h(v - h2f(h));
      wh[j * NINP_ + k] = h;
      wl[j * NINP_ + k] = lo;
    }
  }
}

// permute K: k' = d*512 + h  <-  reference col h*10 + d; 2-limb fp16, scaled x256
__global__ __launch_bounds__(256) void k_permsplit_w1(const float* __restrict__ w,
                                                      u16* __restrict__ wh, u16* __restrict__ wl) {
  int j = blockIdx.x;                      // [0,512)
#pragma unroll 1
  for (int i = 0; i < 20; i++) {
    int k = threadIdx.x + 256 * i;         // [0,5120)
    int d = k >> 9, h = k & 511;
    float v = w[(size_t)j * KBIG_ + h * ND_ + d] * 256.0f;
    u16 a = f2h(v);
    u16 b = f2h(v - h2f(a));
    wh[(size_t)j * KBIG_ + k] = a;
    wl[(size_t)j * KBIG_ + k] = b;
  }
}

__global__ __launch_bounds__(256) void k_permsplit_wo(const float* __restrict__ w,
                                                      u16* __restrict__ wh, u16* __restrict__ wl) {
  int j = blockIdx.x;                      // [0,32)
#pragma unroll 1
  for (int i = 0; i < 20; i++) {
    int k = threadIdx.x + 256 * i;
    int d = k >> 9, h = k & 511;
    float v = (j < NOUT_) ? w[(size_t)j * KBIG_ + h * ND_ + d] * 256.0f : 0.f;
    u16 a = f2h(v);
    u16 b = f2h(v - h2f(a));
    wh[(size_t)j * KBIG_ + k] = a;
    wl[(size_t)j * KBIG_ + k] = b;
  }
}

// ---------------- GEMM 0: cur1 = X @ W0^T  (fp16 2x2 split, 3 terms, BK=32) ----------------

__global__ __launch_bounds__(256) void k_gemm0(const u16* __restrict__ Xh, const u16* __restrict__ Xl,
                                               const u16* __restrict__ Wh, const u16* __restrict__ Wl,
                                               float* __restrict__ out) {
  __shared__ alignas(16) u16 lAh[128 * 32], lAl[128 * 32], lBh[128 * 32], lBl[128 * 32];
  const int tid = threadIdx.x, lane = tid & 63, wid = tid >> 6;
  const int m0 = blockIdx.y * 128, n0 = blockIdx.x * 128;
  const int wr = wid >> 1, wc = wid & 1;
  const int srow = lane >> 2;
  const int sk = 8 * ((lane & 3) ^ ((lane >> 3) & 3));  // source-side XOR swizzle (16B units)
  const int fr = lane & 15, kb = lane >> 4;
  int aoff[4], boff[4];
#pragma unroll
  for (int f = 0; f < 4; f++) {
    int row = wr * 64 + f * 16 + fr;
    aoff[f] = row * 32 + (kb ^ ((row >> 1) & 3)) * 8;
    int col = wc * 64 + f * 16 + fr;
    boff[f] = col * 32 + (kb ^ ((col >> 1) & 3)) * 8;
  }
  f32x4 acc[4][4] = {};
#pragma unroll 1
  for (int kk = 0; kk < NINP_ / 32; kk++) {
    const int k0 = kk * 32;
#pragma unroll
    for (int i = 0; i < 2; i++) {
      int c = wid + 4 * i;
      int ga = (m0 + c * 16 + srow) * NINP_ + k0 + sk;
      gload16(Xh + ga, &lAh[c * 512]);
      gload16(Xl + ga, &lAl[c * 512]);
      int gb = (n0 + c * 16 + srow) * NINP_ + k0 + sk;
      gload16(Wh + gb, &lBh[c * 512]);
      gload16(Wl + gb, &lBl[c * 512]);
    }
    asm volatile("s_waitcnt vmcnt(0)" ::: "memory");
    __syncthreads();
    u16x8 bh[4], bl[4];
#pragma unroll
    for (int j = 0; j < 4; j++) {
      bh[j] = *(const u16x8*)&lBh[boff[j]];
      bl[j] = *(const u16x8*)&lBl[boff[j]];
    }
#pragma unroll
    for (int i = 0; i < 4; i++) {
      u16x8 ah = *(const u16x8*)&lAh[aoff[i]];
      u16x8 al = *(const u16x8*)&lAl[aoff[i]];
#pragma unroll
      for (int j = 0; j < 4; j++) {
        mfma_h(acc[i][j], ah, bh[j]);
        mfma_h(acc[i][j], ah, bl[j]);
        mfma_h(acc[i][j], al, bh[j]);
        // al@bl dropped: <= 2^-22 relative, far below fp32 accumulation noise
      }
    }
    __syncthreads();
  }
  asm volatile("s_nop 7\n\ts_nop 7" ::: "memory");
#pragma unroll
  for (int i = 0; i < 4; i++) {
    int row = m0 + wr * 64 + i * 16 + (lane >> 4) * 4;
#pragma unroll
    for (int j = 0; j < 4; j++) {
      int col = n0 + wc * 64 + j * 16 + fr;
#pragma unroll
      for (int r = 0; r < 4; r++)
        out[(row + r) * H_ + col] = acc[i][j][r] * (1.0f / 256.0f);  // undo W0 scale (exact)
    }
  }
}

// ---------------- GEMM spk: cur2 = gather(S1) @ (W1h+W1l)^T  (R3-proven, BK=64, 908 TF) ----------------

__global__ __launch_bounds__(256) void k_gemm_spk(const u16* __restrict__ S, const u16* __restrict__ Wh,
                                                  const u16* __restrict__ Wl, float* __restrict__ out) {
  __shared__ alignas(16) u16 lA[128 * 64], lBh[128 * 64], lBl[128 * 64];  // 48 KB
  const int tid = threadIdx.x, lane = tid & 63, wid = tid >> 6;
  const int mt = blockIdx.y;
  const int m0 = mt * 128, n0 = blockIdx.x * 128;
  const int t = mt >> 1, brow0 = (mt & 1) * 128;
  const int wr = wid >> 1, wc = wid & 1;
  // staging: each gload stages 8 rows x 128B; lane -> (row = lane>>3, slot = lane&7)
  const int srow8 = lane >> 3;
  const int ksrc = ((lane >> 2) & 1) * 32 + 8 * ((lane & 3) ^ ((lane >> 4) & 3));
  const int fr = lane & 15, kb = lane >> 4;
  const int kx = (kb ^ ((fr >> 1) & 3)) * 8;  // swizzled 16B slot within 32-K half
  int aoff[4], boff[4];
#pragma unroll
  for (int f = 0; f < 4; f++) {
    aoff[f] = (wr * 64 + f * 16 + fr) * 64 + kx;
    boff[f] = (wc * 64 + f * 16 + fr) * 64 + kx;
  }
  f32x4 acc[4][4] = {};
#pragma unroll 1
  for (int kk = 0; kk < KBIG_ / 64; kk++) {
    const int k0 = kk * 64;
    const int d = k0 >> 9, h0 = k0 & 511;
    const int p = t + 4 * d;  // S plane; planes [0,40) are zero history
    const u16* Sb = S + (size_t)(p * 256 + brow0) * 512 + h0 + ksrc;
#pragma unroll
    for (int c = 0; c < 4; c++) {
      int rb = c * 32 + wid * 8;
      gload16(Sb + (rb + srow8) * 512, &lA[rb * 64]);
      size_t gb = (size_t)(n0 + rb + srow8) * KBIG_ + k0 + ksrc;
      gload16(Wh + gb, &lBh[rb * 64]);
      gload16(Wl + gb, &lBl[rb * 64]);
    }
    asm volatile("s_waitcnt vmcnt(0)" ::: "memory");
    __syncthreads();
#pragma unroll
    for (int s = 0; s < 2; s++) {
      const int so = s * 32;
      u16x8 bh[4], bl[4];
#pragma unroll
      for (int j = 0; j < 4; j++) {
        bh[j] = *(const u16x8*)&lBh[boff[j] + so];
        bl[j] = *(const u16x8*)&lBl[boff[j] + so];
      }
#pragma unroll
      for (int i = 0; i < 4; i++) {
        u16x8 a = *(const u16x8*)&lA[aoff[i] + so];
#pragma unroll
        for (int j = 0; j < 4; j++) {
          mfma_h(acc[i][j], a, bh[j]);
          mfma_h(acc[i][j], a, bl[j]);
        }
      }
    }
    __syncthreads();
  }
  asm volatile("s_nop 7\n\ts_nop 7" ::: "memory");
#pragma unroll
  for (int i = 0; i < 4; i++) {
    int row = m0 + wr * 64 + i * 16 + (lane >> 4) * 4;
#pragma unroll
    for (int j = 0; j < 4; j++) {
      int col = n0 + wc * 64 + j * 16 + fr;
#pragma unroll
      for (int r = 0; r < 4; r++)
        out[(row + r) * H_ + col] = acc[i][j][r] * (1.0f / 256.0f);  // undo W1 scale
    }
  }
}

// ---------------- GEMM out: curo = gather(S2) @ Wop^T  (N=32 padded, 2-limb, BK=32) ----------------

__global__ __launch_bounds__(256) void k_gemm_out(const u16* __restrict__ S, const u16* __restrict__ Wh,
                                                  const u16* __restrict__ Wl, float* __restrict__ out) {
  __shared__ alignas(16) u16 lA[128 * 32], lBh[32 * 32], lBl[32 * 32];
  const int tid = threadIdx.x, lane = tid & 63, wid = tid >> 6;
  const int mt = blockIdx.x;
  const int m0 = mt * 128;
  const int t = mt >> 1, brow0 = (mt & 1) * 128;
  const int srow = lane >> 2;
  const int sk = 8 * ((lane & 3) ^ ((lane >> 3) & 3));
  const int fr = lane & 15, kb = lane >> 4;
  int aoff[2], boff[2];
#pragma unroll
  for (int f = 0; f < 2; f++) {
    int row = wid * 32 + f * 16 + fr;
    aoff[f] = row * 32 + (kb ^ ((row >> 1) & 3)) * 8;
    int col = f * 16 + fr;
    boff[f] = col * 32 + (kb ^ ((col >> 1) & 3)) * 8;
  }
  f32x4 acc[2][2] = {};
#pragma unroll 1
  for (int kk = 0; kk < KBIG_ / 32; kk++) {
    const int k0 = kk * 32;
    const int d = k0 >> 9, h0 = k0 & 511;
    const int p = t + 4 * d;
#pragma unroll
    for (int i = 0; i < 2; i++) {
      int c = wid + 4 * i;
      gload16(S + ((size_t)(p * 256 + brow0 + c * 16 + srow) * 512 + h0 + sk), &lA[c * 512]);
    }
    {  // 4 B chunks (2 buffers x 2 halves) over 4 waves
      const u16* bs = (wid < 2) ? Wh : Wl;
      u16* bd = (wid < 2) ? (u16*)lBh : (u16*)lBl;
      int half = wid & 1;
      gload16(bs + (size_t)(half * 16 + srow) * KBIG_ + k0 + sk, &bd[half * 512]);
    }
    asm volatile("s_waitcnt vmcnt(0)" ::: "memory");
    __syncthreads();
    u16x8 bh[2], bl[2];
#pragma unroll
    for (int j = 0; j < 2; j++) {
      bh[j] = *(const u16x8*)&lBh[boff[j]];
      bl[j] = *(const u16x8*)&lBl[boff[j]];
    }
#pragma unroll
    for (int i = 0; i < 2; i++) {
      u16x8 a = *(const u16x8*)&lA[aoff[i]];
#pragma unroll
      for (int j = 0; j < 2; j++) {
        mfma_h(acc[i][j], a, bh[j]);
        mfma_h(acc[i][j], a, bl[j]);
      }
    }
    __syncthreads();
  }
  asm volatile("s_nop 7\n\ts_nop 7" ::: "memory");
#pragma unroll
  for (int i = 0; i < 2; i++) {
    int row = m0 + wid * 32 + i * 16 + (lane >> 4) * 4;
#pragma unroll
    for (int j = 0; j < 2; j++) {
      int col = j * 16 + fr;
#pragma unroll
      for (int r = 0; r < 4; r++)
        out[(row + r) * NOUTP_ + col] = acc[i][j][r] * (1.0f / 256.0f);  // undo Wo scale
    }
  }
}

// ---------------- elementwise LIF scans (strict fp32 rounding; 5-wide load groups for MLP) ----------------

__global__ void k_scan(const float* __restrict__ cur, const float* __restrict__ tau, u16* __restrict__ S) {
  int g = blockIdx.x * 256 + threadIdx.x;   // [0, 131072)
  int b = g >> 9, h = g & 511;
  float a = (float)(1.0 / (1.0 + exp(-(double)tau[h])));
  float mem = 0.f, s = 0.f;
#pragma unroll 1
  for (int tt = 0; tt < 20; tt++) {
    float c[5];
#pragma unroll
    for (int q = 0; q < 5; q++)
      c[q] = cur[((tt * 5 + q) * 256 + b) * 512 + h];   // independent of the recurrence -> 5-deep MLP
    u16 sv[5];
#pragma unroll
    for (int q = 0; q < 5; q++) {
      mem = __fadd_rn(__fmul_rn(__fmul_rn(mem, a), __fsub_rn(1.f, s)), c[q]);
      float x = __fsub_rn(mem, THRESH_);
      s = (x > 0.f) ? 1.f : 0.f;
      mem = (mem < THRESH_) ? mem : 0.f;
      sv[q] = (x > 0.f) ? (u16)0x3C00 : (u16)0;  // fp16 1.0
    }
#pragma unroll
    for (int q = 0; q < 5; q++)
      S[((tt * 5 + q + 40) * 256 + b) * 512 + h] = sv[q];
  }
}

__global__ void k_scan_o(const float* __restrict__ curo, const float* __restrict__ tau, float* __restrict__ outp) {
  int b = blockIdx.x * 64 + threadIdx.x;
  if (b >= B_) return;
  float ao[NOUT_], mem[NOUT_], spk[NOUT_], osum[NOUT_], mot[NOUT_];
#pragma unroll
  for (int j = 0; j < NOUT_; j++) {
    ao[j] = (float)(1.0 / (1.0 + exp(-(double)tau[j])));
    mem[j] = 0.f; spk[j] = 0.f; osum[j] = 0.f; mot[j] = 0.f;
  }
#pragma unroll 1
  for (int t = 0; t < WIN_; t++) {
    const float4* rowp = (const float4*)&curo[(t * 256 + b) * NOUTP_];
    float4 v[5];
#pragma unroll
    for (int q = 0; q < 5; q++) v[q] = rowp[q];
    float cv[NOUT_];
#pragma unroll
    for (int q = 0; q < 5; q++) {
      cv[4 * q + 0] = v[q].x; cv[4 * q + 1] = v[q].y;
      cv[4 * q + 2] = v[q].z; cv[4 * q + 3] = v[q].w;
    }
#pragma unroll
    for (int j = 0; j < NOUT_; j++) {
      mem[j] = __fadd_rn(__fmul_rn(__fmul_rn(mem[j], ao[j]), __fsub_rn(1.f, spk[j])), cv[j]);
      float x = __fsub_rn(mem[j], THRESH_);
      spk[j] = (x > 0.f) ? 1.f : 0.f;
      mem[j] = (mem[j] < THRESH_) ? mem[j] : 0.f;
      osum[j] = __fadd_rn(osum[j], spk[j]);
    }
    float mx = -1e30f;
#pragma unroll
    for (int j = 0; j < NOUT_; j++) mx = fmaxf(mx, mem[j]);
    float se = 0.f, e[NOUT_];
#pragma unroll
    for (int j = 0; j < NOUT_; j++) { e[j] = expf(__fsub_rn(mem[j], mx)); se = __fadd_rn(se, e[j]); }
#pragma unroll
    for (int j = 0; j < NOUT_; j++) mot[j] = __fadd_rn(mot[j], __fdiv_rn(e[j], se));
  }
#pragma unroll
  for (int j = 0; j < NOUT_; j++) {
    outp[b * NOUT_ + j] = __fdiv_rn(osum[j], 100.0f);
    outp[B_ * NOUT_ + b * NOUT_ + j] = mot[j];
  }
}

// ---------------- launch ----------------
// Workspace aliasing (liveness-based, ~177MB, proven R5-R7):
//   region0 (72.1MB): Xh+Xl -> dead after k_gemm0 -> cur2 (52.4MB)
//   region1 (52.4MB): cur1  -> dead after scan1   -> S2   (36.7MB)

extern "C" void kernel_launch(void* const* d_in, const int* in_sizes, int n_in,
                              void* d_out, int out_size, void* d_ws, size_t ws_size,
                              hipStream_t stream) {
  const float* in   = (const float*)d_in[0];
  const float* W0   = (const float*)d_in[1];
  const float* W1   = (const float*)d_in[2];
  const float* Wo   = (const float*)d_in[3];
  const float* tau1 = (const float*)d_in[4];
  const float* tau2 = (const float*)d_in[5];
  const float* tauo = (const float*)d_in[6];
  float* out = (float*)d_out;

  char* ws = (char*)d_ws;
  size_t off = 0;
  auto take = [&](size_t bytes) -> char* {
    char* p = ws + off;
    off += (bytes + 255) & ~(size_t)255;
    return p;
  };
  char* region0 = take((size_t)2 * M_ * NINP_ * 2);        // Xh|Xl, later cur2
  u16* Xh  = (u16*)region0;
  u16* Xl  = (u16*)(region0 + (size_t)M_ * NINP_ * 2);
  float* cur2 = (float*)region0;                           // alias (after gemm0)
  char* region1 = take((size_t)M_ * H_ * 4);               // cur1, later S2
  float* cur1 = (float*)region1;
  u16* S2 = (u16*)region1;                                 // alias (after scan1)
  u16* W0h = (u16*)take((size_t)H_ * NINP_ * 2);
  u16* W0l = (u16*)take((size_t)H_ * NINP_ * 2);
  u16* W1h = (u16*)take((size_t)H_ * KBIG_ * 2);
  u16* W1l = (u16*)take((size_t)H_ * KBIG_ * 2);
  u16* Woh = (u16*)take((size_t)NOUTP_ * KBIG_ * 2);
  u16* Wol = (u16*)take((size_t)NOUTP_ * KBIG_ * 2);
  float* curo = (float*)take((size_t)M_ * NOUTP_ * 4);
  u16* S1 = (u16*)take((size_t)PLANES_ * B_ * H_ * 2);     // plain fp16 spikes

  // zero S1 history planes [0,40)
  hipMemsetAsync(S1, 0, (size_t)40 * B_ * H_ * 2, stream);

  k_split_x<<<dim3(M_), 256, 0, stream>>>(in, Xh, Xl);
  k_split_w0<<<dim3(H_), 256, 0, stream>>>(W0, W0h, W0l);
  k_permsplit_w1<<<dim3(H_), 256, 0, stream>>>(W1, W1h, W1l);
  k_permsplit_wo<<<dim3(NOUTP_), 256, 0, stream>>>(Wo, Woh, Wol);

  k_gemm0<<<dim3(4, 200), 256, 0, stream>>>(Xh, Xl, W0h, W0l, cur1);
  k_scan<<<dim3(512), 256, 0, stream>>>(cur1, tau1, S1);
  // cur1 dead; zero S2 history planes [0,40) in its place
  hipMemsetAsync(S2, 0, (size_t)40 * B_ * H_ * 2, stream);
  // Xh/Xl dead; cur2 overwrites region0
  k_gemm_spk<<<dim3(4, 200), 256, 0, stream>>>(S1, W1h, W1l, cur2);
  k_scan<<<dim3(512), 256, 0, stream>>>(cur2, tau2, S2);
  k_gemm_out<<<dim3(200), 256, 0, stream>>>(S2, Woh, Wol, curo);
  k_scan_o<<<dim3(4), 64, 0, stream>>>(curo, tauo, out);
}

// Round 10
// 652.279 us; speedup vs baseline: 1.3803x; 1.0169x over previous
//
#include <hip/hip_runtime.h>
#include <stdint.h>

#define THRESH_ 0.3f
constexpr int B_ = 256, WIN_ = 100, NIN_ = 700, NINP_ = 704, H_ = 512;
constexpr int NOUT_ = 20, NOUTP_ = 32, ND_ = 10, KBIG_ = 5120, M_ = 25600;
constexpr int PLANES_ = 140;   // 40 zero-history + 100

typedef unsigned short u16;
typedef unsigned int u32;
typedef unsigned short u16x8 __attribute__((ext_vector_type(8)));
typedef float f32x4 __attribute__((ext_vector_type(4)));

// ---- fp16 RNE split ----
__device__ __forceinline__ u16 f2h(float f) {
  _Float16 h = (_Float16)f;           // RNE
  union { _Float16 h; u16 u; } v; v.h = h;
  return v.u;
}
__device__ __forceinline__ float h2f(u16 u) {
  union { u16 u; _Float16 h; } v; v.u = u;
  return (float)v.h;
}

__device__ __forceinline__ void mfma_h(f32x4& acc, u16x8 a, u16x8 b) {
  asm volatile("v_mfma_f32_16x16x32_f16 %0, %1, %2, %0" : "+v"(acc) : "v"(a), "v"(b));
}
__device__ __forceinline__ void gload16(const void* g, void* l) {
  __builtin_amdgcn_global_load_lds(
      (const __attribute__((address_space(1))) unsigned int*)g,
      (__attribute__((address_space(3))) unsigned int*)l, 16, 0, 0);
}

// ---------------- X split (R8-proven) ----------------

__global__ __launch_bounds__(256) void k_split_x(const float* __restrict__ in,
                                                 u16* __restrict__ xh, u16* __restrict__ xl) {
  int r = blockIdx.x;                      // [0,25600), r = t*256 + b
  int t = r >> 8, b = r & 255;
  const float* src = in + (size_t)(b * WIN_ + t) * NIN_;
#pragma unroll
  for (int i = 0; i < 3; i++) {
    int k = threadIdx.x + 256 * i;
    if (k < NINP_) {
      float v = (k < NIN_) ? src[k] : 0.f;
      u16 h = f2h(v);
      u16 lo = f2h(v - h2f(h));
      xh[(size_t)r * NINP_ + k] = h;
      xl[(size_t)r * NINP_ + k] = lo;
    }
  }
}

// ---------------- merged weight prep (one launch; verbatim R8 math) ----------------
// blocks [0,512): W0 split (scaled x256, zero-pad k>=700)
// blocks [512,1024): W1 perm+split  k' = d*512+h
// blocks [1024,1056): Wo perm+split (rows >=20 zero)

__global__ __launch_bounds__(256) void k_prep_w(const float* __restrict__ W0,
                                                const float* __restrict__ W1,
                                                const float* __restrict__ Wo,
                                                u16* __restrict__ w0h, u16* __restrict__ w0l,
                                                u16* __restrict__ w1h, u16* __restrict__ w1l,
                                                u16* __restrict__ woh, u16* __restrict__ wol) {
  int bid = blockIdx.x;
  if (bid < 512) {
    int j = bid;
#pragma unroll
    for (int i = 0; i < 3; i++) {
      int k = threadIdx.x + 256 * i;
      if (k < NINP_) {
        float v = (k < NIN_) ? W0[j * NIN_ + k] * 256.0f : 0.f;
        u16 h = f2h(v);
        u16 lo = f2h(v - h2f(h));
        w0h[j * NINP_ + k] = h;
        w0l[j * NINP_ + k] = lo;
      }
    }
  } else if (bid < 1024) {
    int j = bid - 512;
#pragma unroll 1
    for (int i = 0; i < 20; i++) {
      int k = threadIdx.x + 256 * i;
      int d = k >> 9, h = k & 511;
      float v = W1[(size_t)j * KBIG_ + h * ND_ + d] * 256.0f;
      u16 a = f2h(v);
      u16 b = f2h(v - h2f(a));
      w1h[(size_t)j * KBIG_ + k] = a;
      w1l[(size_t)j * KBIG_ + k] = b;
    }
  } else {
    int j = bid - 1024;
#pragma unroll 1
    for (int i = 0; i < 20; i++) {
      int k = threadIdx.x + 256 * i;
      int d = k >> 9, h = k & 511;
      float v = (j < NOUT_) ? Wo[(size_t)j * KBIG_ + h * ND_ + d] * 256.0f : 0.f;
      u16 a = f2h(v);
      u16 b = f2h(v - h2f(a));
      woh[(size_t)j * KBIG_ + k] = a;
      wol[(size_t)j * KBIG_ + k] = b;
    }
  }
}

// ---------------- GEMM 0: cur1 = X @ W0^T  (R8-proven; grid transposed for XCD affinity) ----------------
// grid (200, 4): m0 = blockIdx.x*128, n0 = blockIdx.y*128. 200 % 8 == 0 => the 4 N-blocks
// sharing an X row-panel have flat ids mt + 200*nt, all with (id & 7) == mt & 7 -> one XCD L2.

__global__ __launch_bounds__(256) void k_gemm0(const u16* __restrict__ Xh, const u16* __restrict__ Xl,
                                               const u16* __restrict__ Wh, const u16* __restrict__ Wl,
                                               float* __restrict__ out) {
  __shared__ alignas(16) u16 lAh[128 * 32], lAl[128 * 32], lBh[128 * 32], lBl[128 * 32];
  const int tid = threadIdx.x, lane = tid & 63, wid = tid >> 6;
  const int m0 = blockIdx.x * 128, n0 = blockIdx.y * 128;
  const int wr = wid >> 1, wc = wid & 1;
  const int srow = lane >> 2;
  const int sk = 8 * ((lane & 3) ^ ((lane >> 3) & 3));  // source-side XOR swizzle (16B units)
  const int fr = lane & 15, kb = lane >> 4;
  int aoff[4], boff[4];
#pragma unroll
  for (int f = 0; f < 4; f++) {
    int row = wr * 64 + f * 16 + fr;
    aoff[f] = row * 32 + (kb ^ ((row >> 1) & 3)) * 8;
    int col = wc * 64 + f * 16 + fr;
    boff[f] = col * 32 + (kb ^ ((col >> 1) & 3)) * 8;
  }
  f32x4 acc[4][4] = {};
#pragma unroll 1
  for (int kk = 0; kk < NINP_ / 32; kk++) {
    const int k0 = kk * 32;
#pragma unroll
    for (int i = 0; i < 2; i++) {
      int c = wid + 4 * i;
      int ga = (m0 + c * 16 + srow) * NINP_ + k0 + sk;
      gload16(Xh + ga, &lAh[c * 512]);
      gload16(Xl + ga, &lAl[c * 512]);
      int gb = (n0 + c * 16 + srow) * NINP_ + k0 + sk;
      gload16(Wh + gb, &lBh[c * 512]);
      gload16(Wl + gb, &lBl[c * 512]);
    }
    asm volatile("s_waitcnt vmcnt(0)" ::: "memory");
    __syncthreads();
    u16x8 bh[4], bl[4];
#pragma unroll
    for (int j = 0; j < 4; j++) {
      bh[j] = *(const u16x8*)&lBh[boff[j]];
      bl[j] = *(const u16x8*)&lBl[boff[j]];
    }
#pragma unroll
    for (int i = 0; i < 4; i++) {
      u16x8 ah = *(const u16x8*)&lAh[aoff[i]];
      u16x8 al = *(const u16x8*)&lAl[aoff[i]];
#pragma unroll
      for (int j = 0; j < 4; j++) {
        mfma_h(acc[i][j], ah, bh[j]);
        mfma_h(acc[i][j], ah, bl[j]);
        mfma_h(acc[i][j], al, bh[j]);
        // al@bl dropped: <= 2^-22 relative, far below fp32 accumulation noise
      }
    }
    __syncthreads();
  }
  asm volatile("s_nop 7\n\ts_nop 7" ::: "memory");
#pragma unroll
  for (int i = 0; i < 4; i++) {
    int row = m0 + wr * 64 + i * 16 + (lane >> 4) * 4;
#pragma unroll
    for (int j = 0; j < 4; j++) {
      int col = n0 + wc * 64 + j * 16 + fr;
#pragma unroll
      for (int r = 0; r < 4; r++)
        out[(row + r) * H_ + col] = acc[i][j][r] * (1.0f / 256.0f);  // undo W0 scale (exact)
    }
  }
}

// ---------------- GEMM spk: cur2 = gather(S1) @ (W1h+W1l)^T  (R8 core; grid transposed) ----------------

__global__ __launch_bounds__(256) void k_gemm_spk(const u16* __restrict__ S, const u16* __restrict__ Wh,
                                                  const u16* __restrict__ Wl, float* __restrict__ out) {
  __shared__ alignas(16) u16 lA[128 * 64], lBh[128 * 64], lBl[128 * 64];  // 48 KB
  const int tid = threadIdx.x, lane = tid & 63, wid = tid >> 6;
  const int mt = blockIdx.x;                  // grid (200,4): XCD affinity via 200%8==0
  const int m0 = mt * 128, n0 = blockIdx.y * 128;
  const int t = mt >> 1, brow0 = (mt & 1) * 128;
  const int wr = wid >> 1, wc = wid & 1;
  // staging: each gload stages 8 rows x 128B; lane -> (row = lane>>3, slot = lane&7)
  const int srow8 = lane >> 3;
  const int ksrc = ((lane >> 2) & 1) * 32 + 8 * ((lane & 3) ^ ((lane >> 4) & 3));
  const int fr = lane & 15, kb = lane >> 4;
  const int kx = (kb ^ ((fr >> 1) & 3)) * 8;  // swizzled 16B slot within 32-K half
  int aoff[4], boff[4];
#pragma unroll
  for (int f = 0; f < 4; f++) {
    aoff[f] = (wr * 64 + f * 16 + fr) * 64 + kx;
    boff[f] = (wc * 64 + f * 16 + fr) * 64 + kx;
  }
  f32x4 acc[4][4] = {};
#pragma unroll 1
  for (int kk = 0; kk < KBIG_ / 64; kk++) {
    const int k0 = kk * 64;
    const int d = k0 >> 9, h0 = k0 & 511;
    const int p = t + 4 * d;  // S plane; planes [0,40) are zero history
    const u16* Sb = S + (size_t)(p * 256 + brow0) * 512 + h0 + ksrc;
#pragma unroll
    for (int c = 0; c < 4; c++) {
      int rb = c * 32 + wid * 8;
      gload16(Sb + (rb + srow8) * 512, &lA[rb * 64]);
      size_t gb = (size_t)(n0 + rb + srow8) * KBIG_ + k0 + ksrc;
      gload16(Wh + gb, &lBh[rb * 64]);
      gload16(Wl + gb, &lBl[rb * 64]);
    }
    asm volatile("s_waitcnt vmcnt(0)" ::: "memory");
    __syncthreads();
#pragma unroll
    for (int s = 0; s < 2; s++) {
      const int so = s * 32;
      u16x8 bh[4], bl[4];
#pragma unroll
      for (int j = 0; j < 4; j++) {
        bh[j] = *(const u16x8*)&lBh[boff[j] + so];
        bl[j] = *(const u16x8*)&lBl[boff[j] + so];
      }
#pragma unroll
      for (int i = 0; i < 4; i++) {
        u16x8 a = *(const u16x8*)&lA[aoff[i] + so];
#pragma unroll
        for (int j = 0; j < 4; j++) {
          mfma_h(acc[i][j], a, bh[j]);
          mfma_h(acc[i][j], a, bl[j]);
        }
      }
    }
    __syncthreads();
  }
  asm volatile("s_nop 7\n\ts_nop 7" ::: "memory");
#pragma unroll
  for (int i = 0; i < 4; i++) {
    int row = m0 + wr * 64 + i * 16 + (lane >> 4) * 4;
#pragma unroll
    for (int j = 0; j < 4; j++) {
      int col = n0 + wc * 64 + j * 16 + fr;
#pragma unroll
      for (int r = 0; r < 4; r++)
        out[(row + r) * H_ + col] = acc[i][j][r] * (1.0f / 256.0f);  // undo W1 scale
    }
  }
}

// ---------------- GEMM out: curo = gather(S2) @ Wop^T  (N=32 padded, 2-limb, BK=32) ----------------

__global__ __launch_bounds__(256) void k_gemm_out(const u16* __restrict__ S, const u16* __restrict__ Wh,
                                                  const u16* __restrict__ Wl, float* __restrict__ out) {
  __shared__ alignas(16) u16 lA[128 * 32], lBh[32 * 32], lBl[32 * 32];
  const int tid = threadIdx.x, lane = tid & 63, wid = tid >> 6;
  const int mt = blockIdx.x;
  const int m0 = mt * 128;
  const int t = mt >> 1, brow0 = (mt & 1) * 128;
  const int srow = lane >> 2;
  const int sk = 8 * ((lane & 3) ^ ((lane >> 3) & 3));
  const int fr = lane & 15, kb = lane >> 4;
  int aoff[2], boff[2];
#pragma unroll
  for (int f = 0; f < 2; f++) {
    int row = wid * 32 + f * 16 + fr;
    aoff[f] = row * 32 + (kb ^ ((row >> 1) & 3)) * 8;
    int col = f * 16 + fr;
    boff[f] = col * 32 + (kb ^ ((col >> 1) & 3)) * 8;
  }
  f32x4 acc[2][2] = {};
#pragma unroll 1
  for (int kk = 0; kk < KBIG_ / 32; kk++) {
    const int k0 = kk * 32;
    const int d = k0 >> 9, h0 = k0 & 511;
    const int p = t + 4 * d;
#pragma unroll
    for (int i = 0; i < 2; i++) {
      int c = wid + 4 * i;
      gload16(S + ((size_t)(p * 256 + brow0 + c * 16 + srow) * 512 + h0 + sk), &lA[c * 512]);
    }
    {  // 4 B chunks (2 buffers x 2 halves) over 4 waves
      const u16* bs = (wid < 2) ? Wh : Wl;
      u16* bd = (wid < 2) ? (u16*)lBh : (u16*)lBl;
      int half = wid & 1;
      gload16(bs + (size_t)(half * 16 + srow) * KBIG_ + k0 + sk, &bd[half * 512]);
    }
    asm volatile("s_waitcnt vmcnt(0)" ::: "memory");
    __syncthreads();
    u16x8 bh[2], bl[2];
#pragma unroll
    for (int j = 0; j < 2; j++) {
      bh[j] = *(const u16x8*)&lBh[boff[j]];
      bl[j] = *(const u16x8*)&lBl[boff[j]];
    }
#pragma unroll
    for (int i = 0; i < 2; i++) {
      u16x8 a = *(const u16x8*)&lA[aoff[i]];
#pragma unroll
      for (int j = 0; j < 2; j++) {
        mfma_h(acc[i][j], a, bh[j]);
        mfma_h(acc[i][j], a, bl[j]);
      }
    }
    __syncthreads();
  }
  asm volatile("s_nop 7\n\ts_nop 7" ::: "memory");
#pragma unroll
  for (int i = 0; i < 2; i++) {
    int row = m0 + wid * 32 + i * 16 + (lane >> 4) * 4;
#pragma unroll
    for (int j = 0; j < 2; j++) {
      int col = j * 16 + fr;
#pragma unroll
      for (int r = 0; r < 4; r++)
        out[(row + r) * NOUTP_ + col] = acc[i][j][r] * (1.0f / 256.0f);  // undo Wo scale
    }
  }
}

// ---------------- elementwise LIF scans (strict fp32 rounding; 5-wide load groups) ----------------

__global__ void k_scan(const float* __restrict__ cur, const float* __restrict__ tau, u16* __restrict__ S) {
  int g = blockIdx.x * 256 + threadIdx.x;   // [0, 131072)
  int b = g >> 9, h = g & 511;
  float a = (float)(1.0 / (1.0 + exp(-(double)tau[h])));
  float mem = 0.f, s = 0.f;
#pragma unroll 1
  for (int tt = 0; tt < 20; tt++) {
    float c[5];
#pragma unroll
    for (int q = 0; q < 5; q++)
      c[q] = cur[((tt * 5 + q) * 256 + b) * 512 + h];   // independent of the recurrence
    u16 sv[5];
#pragma unroll
    for (int q = 0; q < 5; q++) {
      mem = __fadd_rn(__fmul_rn(__fmul_rn(mem, a), __fsub_rn(1.f, s)), c[q]);
      float x = __fsub_rn(mem, THRESH_);
      s = (x > 0.f) ? 1.f : 0.f;
      mem = (mem < THRESH_) ? mem : 0.f;
      sv[q] = (x > 0.f) ? (u16)0x3C00 : (u16)0;  // fp16 1.0
    }
#pragma unroll
    for (int q = 0; q < 5; q++)
      S[((tt * 5 + q + 40) * 256 + b) * 512 + h] = sv[q];
  }
}

__global__ void k_scan_o(const float* __restrict__ curo, const float* __restrict__ tau, float* __restrict__ outp) {
  int b = blockIdx.x * 64 + threadIdx.x;
  if (b >= B_) return;
  float ao[NOUT_], mem[NOUT_], spk[NOUT_], osum[NOUT_], mot[NOUT_];
#pragma unroll
  for (int j = 0; j < NOUT_; j++) {
    ao[j] = (float)(1.0 / (1.0 + exp(-(double)tau[j])));
    mem[j] = 0.f; spk[j] = 0.f; osum[j] = 0.f; mot[j] = 0.f;
  }
#pragma unroll 1
  for (int t = 0; t < WIN_; t++) {
    const float4* rowp = (const float4*)&curo[(t * 256 + b) * NOUTP_];
    float4 v[5];
#pragma unroll
    for (int q = 0; q < 5; q++) v[q] = rowp[q];
    float cv[NOUT_];
#pragma unroll
    for (int q = 0; q < 5; q++) {
      cv[4 * q + 0] = v[q].x; cv[4 * q + 1] = v[q].y;
      cv[4 * q + 2] = v[q].z; cv[4 * q + 3] = v[q].w;
    }
#pragma unroll
    for (int j = 0; j < NOUT_; j++) {
      mem[j] = __fadd_rn(__fmul_rn(__fmul_rn(mem[j], ao[j]), __fsub_rn(1.f, spk[j])), cv[j]);
      float x = __fsub_rn(mem[j], THRESH_);
      spk[j] = (x > 0.f) ? 1.f : 0.f;
      mem[j] = (mem[j] < THRESH_) ? mem[j] : 0.f;
      osum[j] = __fadd_rn(osum[j], spk[j]);
    }
    float mx = -1e30f;
#pragma unroll
    for (int j = 0; j < NOUT_; j++) mx = fmaxf(mx, mem[j]);
    float se = 0.f, e[NOUT_];
#pragma unroll
    for (int j = 0; j < NOUT_; j++) { e[j] = expf(__fsub_rn(mem[j], mx)); se = __fadd_rn(se, e[j]); }
#pragma unroll
    for (int j = 0; j < NOUT_; j++) mot[j] = __fadd_rn(mot[j], __fdiv_rn(e[j], se));
  }
#pragma unroll
  for (int j = 0; j < NOUT_; j++) {
    outp[b * NOUT_ + j] = __fdiv_rn(osum[j], 100.0f);
    outp[B_ * NOUT_ + b * NOUT_ + j] = mot[j];
  }
}

// ---------------- launch ----------------
// Workspace aliasing (liveness-based, ~177MB, proven R5-R8):
//   region0 (72.1MB): Xh+Xl -> dead after k_gemm0 -> cur2 (52.4MB)
//   region1 (52.4MB): cur1  -> dead after scan1   -> S2   (36.7MB)

extern "C" void kernel_launch(void* const* d_in, const int* in_sizes, int n_in,
                              void* d_out, int out_size, void* d_ws, size_t ws_size,
                              hipStream_t stream) {
  const float* in   = (const float*)d_in[0];
  const float* W0   = (const float*)d_in[1];
  const float* W1   = (const float*)d_in[2];
  const float* Wo   = (const float*)d_in[3];
  const float* tau1 = (const float*)d_in[4];
  const float* tau2 = (const float*)d_in[5];
  const float* tauo = (const float*)d_in[6];
  float* out = (float*)d_out;

  char* ws = (char*)d_ws;
  size_t off = 0;
  auto take = [&](size_t bytes) -> char* {
    char* p = ws + off;
    off += (bytes + 255) & ~(size_t)255;
    return p;
  };
  char* region0 = take((size_t)2 * M_ * NINP_ * 2);        // Xh|Xl, later cur2
  u16* Xh  = (u16*)region0;
  u16* Xl  = (u16*)(region0 + (size_t)M_ * NINP_ * 2);
  float* cur2 = (float*)region0;                           // alias (after gemm0)
  char* region1 = take((size_t)M_ * H_ * 4);               // cur1, later S2
  float* cur1 = (float*)region1;
  u16* S2 = (u16*)region1;                                 // alias (after scan1)
  u16* W0h = (u16*)take((size_t)H_ * NINP_ * 2);
  u16* W0l = (u16*)take((size_t)H_ * NINP_ * 2);
  u16* W1h = (u16*)take((size_t)H_ * KBIG_ * 2);
  u16* W1l = (u16*)take((size_t)H_ * KBIG_ * 2);
  u16* Woh = (u16*)take((size_t)NOUTP_ * KBIG_ * 2);
  u16* Wol = (u16*)take((size_t)NOUTP_ * KBIG_ * 2);
  float* curo = (float*)take((size_t)M_ * NOUTP_ * 4);
  u16* S1 = (u16*)take((size_t)PLANES_ * B_ * H_ * 2);     // plain fp16 spikes

  // zero S1 history planes [0,40)
  hipMemsetAsync(S1, 0, (size_t)40 * B_ * H_ * 2, stream);

  k_prep_w<<<dim3(1056), 256, 0, stream>>>(W0, W1, Wo, W0h, W0l, W1h, W1l, Woh, Wol);
  k_split_x<<<dim3(M_), 256, 0, stream>>>(in, Xh, Xl);

  k_gemm0<<<dim3(200, 4), 256, 0, stream>>>(Xh, Xl, W0h, W0l, cur1);
  k_scan<<<dim3(512), 256, 0, stream>>>(cur1, tau1, S1);
  // cur1 dead; zero S2 history planes [0,40) in its place
  hipMemsetAsync(S2, 0, (size_t)40 * B_ * H_ * 2, stream);
  // Xh/Xl dead; cur2 overwrites region0
  k_gemm_spk<<<dim3(200, 4), 256, 0, stream>>>(S1, W1h, W1l, cur2);
  k_scan<<<dim3(512), 256, 0, stream>>>(cur2, tau2, S2);
  k_gemm_out<<<dim3(200), 256, 0, stream>>>(S2, Woh, Wol, curo);
  k_scan_o<<<dim3(4), 64, 0, stream>>>(curo, tauo, out);
}

// Round 11
// 638.193 us; speedup vs baseline: 1.4108x; 1.0221x over previous
//
#include <hip/hip_runtime.h>
#include <stdint.h>

#define THRESH_ 0.3f
constexpr int B_ = 256, WIN_ = 100, NIN_ = 700, NINP_ = 704, H_ = 512;
constexpr int NOUT_ = 20, NOUTP_ = 32, ND_ = 10, KBIG_ = 5120, M_ = 25600;
constexpr int PLANES_ = 140;   // 40 zero-history + 100

typedef unsigned short u16;
typedef unsigned int u32;
typedef unsigned short u16x4 __attribute__((ext_vector_type(4)));
typedef unsigned short u16x8 __attribute__((ext_vector_type(8)));
typedef float f32x4 __attribute__((ext_vector_type(4)));

// ---- fp16 RNE split ----
__device__ __forceinline__ u16 f2h(float f) {
  _Float16 h = (_Float16)f;           // RNE
  union { _Float16 h; u16 u; } v; v.h = h;
  return v.u;
}
__device__ __forceinline__ float h2f(u16 u) {
  union { u16 u; _Float16 h; } v; v.u = u;
  return (float)v.h;
}

__device__ __forceinline__ void mfma_h(f32x4& acc, u16x8 a, u16x8 b) {
  asm volatile("v_mfma_f32_16x16x32_f16 %0, %1, %2, %0" : "+v"(acc) : "v"(a), "v"(b));
}
__device__ __forceinline__ void gload16(const void* g, void* l) {
  __builtin_amdgcn_global_load_lds(
      (const __attribute__((address_space(1))) unsigned int*)g,
      (__attribute__((address_space(3))) unsigned int*)l, 16, 0, 0);
}

// ---------------- X split (vectorized: float4 in, u16x4 out; 4 rows/block) ----------------

__global__ __launch_bounds__(256) void k_split_x(const float* __restrict__ in,
                                                 u16* __restrict__ xh, u16* __restrict__ xl) {
  int r = blockIdx.x * 4 + (threadIdx.x >> 6);   // [0,25600), r = t*256 + b
  int l = threadIdx.x & 63;
  int t = r >> 8, b = r & 255;
  const f32x4* src = (const f32x4*)(in + (size_t)(b * WIN_ + t) * NIN_);  // row base % 16B == 0
  u16x4* dh = (u16x4*)(xh + (size_t)r * NINP_);
  u16x4* dl = (u16x4*)(xl + (size_t)r * NINP_);
#pragma unroll
  for (int i = 0; i < 3; i++) {
    int k4 = l + 64 * i;                         // [0,192); valid slots [0,176)
    if (k4 < 176) {
      f32x4 v = (k4 < 175) ? src[k4] : (f32x4){0.f, 0.f, 0.f, 0.f};  // slot 175 = k 700..703 pad
      u16x4 hh, ll;
#pragma unroll
      for (int e = 0; e < 4; e++) {
        u16 h = f2h(v[e]);
        hh[e] = h;
        ll[e] = f2h(v[e] - h2f(h));
      }
      dh[k4] = hh;
      dl[k4] = ll;
    }
  }
}

// ---------------- merged weight prep (one launch; verbatim R8 math) ----------------
// blocks [0,512): W0 split (scaled x256, zero-pad k>=700)
// blocks [512,1024): W1 perm+split  k' = d*512+h
// blocks [1024,1056): Wo perm+split (rows >=20 zero)

__global__ __launch_bounds__(256) void k_prep_w(const float* __restrict__ W0,
                                                const float* __restrict__ W1,
                                                const float* __restrict__ Wo,
                                                u16* __restrict__ w0h, u16* __restrict__ w0l,
                                                u16* __restrict__ w1h, u16* __restrict__ w1l,
                                                u16* __restrict__ woh, u16* __restrict__ wol) {
  int bid = blockIdx.x;
  if (bid < 512) {
    int j = bid;
#pragma unroll
    for (int i = 0; i < 3; i++) {
      int k = threadIdx.x + 256 * i;
      if (k < NINP_) {
        float v = (k < NIN_) ? W0[j * NIN_ + k] * 256.0f : 0.f;
        u16 h = f2h(v);
        u16 lo = f2h(v - h2f(h));
        w0h[j * NINP_ + k] = h;
        w0l[j * NINP_ + k] = lo;
      }
    }
  } else if (bid < 1024) {
    int j = bid - 512;
#pragma unroll 1
    for (int i = 0; i < 20; i++) {
      int k = threadIdx.x + 256 * i;
      int d = k >> 9, h = k & 511;
      float v = W1[(size_t)j * KBIG_ + h * ND_ + d] * 256.0f;
      u16 a = f2h(v);
      u16 b = f2h(v - h2f(a));
      w1h[(size_t)j * KBIG_ + k] = a;
      w1l[(size_t)j * KBIG_ + k] = b;
    }
  } else {
    int j = bid - 1024;
#pragma unroll 1
    for (int i = 0; i < 20; i++) {
      int k = threadIdx.x + 256 * i;
      int d = k >> 9, h = k & 511;
      float v = (j < NOUT_) ? Wo[(size_t)j * KBIG_ + h * ND_ + d] * 256.0f : 0.f;
      u16 a = f2h(v);
      u16 b = f2h(v - h2f(a));
      woh[(size_t)j * KBIG_ + k] = a;
      wol[(size_t)j * KBIG_ + k] = b;
    }
  }
}

// ---------------- GEMM 0: cur1 = X @ W0^T  (grid (200,4) for XCD affinity) ----------------

__global__ __launch_bounds__(256) void k_gemm0(const u16* __restrict__ Xh, const u16* __restrict__ Xl,
                                               const u16* __restrict__ Wh, const u16* __restrict__ Wl,
                                               float* __restrict__ out) {
  __shared__ alignas(16) u16 lAh[128 * 32], lAl[128 * 32], lBh[128 * 32], lBl[128 * 32];
  const int tid = threadIdx.x, lane = tid & 63, wid = tid >> 6;
  const int m0 = blockIdx.x * 128, n0 = blockIdx.y * 128;
  const int wr = wid >> 1, wc = wid & 1;
  const int srow = lane >> 2;
  const int sk = 8 * ((lane & 3) ^ ((lane >> 3) & 3));  // source-side XOR swizzle (16B units)
  const int fr = lane & 15, kb = lane >> 4;
  int aoff[4], boff[4];
#pragma unroll
  for (int f = 0; f < 4; f++) {
    int row = wr * 64 + f * 16 + fr;
    aoff[f] = row * 32 + (kb ^ ((row >> 1) & 3)) * 8;
    int col = wc * 64 + f * 16 + fr;
    boff[f] = col * 32 + (kb ^ ((col >> 1) & 3)) * 8;
  }
  f32x4 acc[4][4] = {};
#pragma unroll 1
  for (int kk = 0; kk < NINP_ / 32; kk++) {
    const int k0 = kk * 32;
#pragma unroll
    for (int i = 0; i < 2; i++) {
      int c = wid + 4 * i;
      int ga = (m0 + c * 16 + srow) * NINP_ + k0 + sk;
      gload16(Xh + ga, &lAh[c * 512]);
      gload16(Xl + ga, &lAl[c * 512]);
      int gb = (n0 + c * 16 + srow) * NINP_ + k0 + sk;
      gload16(Wh + gb, &lBh[c * 512]);
      gload16(Wl + gb, &lBl[c * 512]);
    }
    asm volatile("s_waitcnt vmcnt(0)" ::: "memory");
    __syncthreads();
    u16x8 bh[4], bl[4];
#pragma unroll
    for (int j = 0; j < 4; j++) {
      bh[j] = *(const u16x8*)&lBh[boff[j]];
      bl[j] = *(const u16x8*)&lBl[boff[j]];
    }
#pragma unroll
    for (int i = 0; i < 4; i++) {
      u16x8 ah = *(const u16x8*)&lAh[aoff[i]];
      u16x8 al = *(const u16x8*)&lAl[aoff[i]];
#pragma unroll
      for (int j = 0; j < 4; j++) {
        mfma_h(acc[i][j], ah, bh[j]);
        mfma_h(acc[i][j], ah, bl[j]);
        mfma_h(acc[i][j], al, bh[j]);
        // al@bl dropped: <= 2^-22 relative, far below fp32 accumulation noise
      }
    }
    __syncthreads();
  }
  asm volatile("s_nop 7\n\ts_nop 7" ::: "memory");
#pragma unroll
  for (int i = 0; i < 4; i++) {
    int row = m0 + wr * 64 + i * 16 + (lane >> 4) * 4;
#pragma unroll
    for (int j = 0; j < 4; j++) {
      int col = n0 + wc * 64 + j * 16 + fr;
#pragma unroll
      for (int r = 0; r < 4; r++)
        out[(row + r) * H_ + col] = acc[i][j][r] * (1.0f / 256.0f);  // undo W0 scale (exact)
    }
  }
}

// ---------------- GEMM spk: cur2 = gather(S1) @ (W1h+W1l)^T  (R10-proven: BK=64 + XCD grid) ----------------

__global__ __launch_bounds__(256) void k_gemm_spk(const u16* __restrict__ S, const u16* __restrict__ Wh,
                                                  const u16* __restrict__ Wl, float* __restrict__ out) {
  __shared__ alignas(16) u16 lA[128 * 64], lBh[128 * 64], lBl[128 * 64];  // 48 KB
  const int tid = threadIdx.x, lane = tid & 63, wid = tid >> 6;
  const int mt = blockIdx.x;                  // grid (200,4): XCD affinity via 200%8==0
  const int m0 = mt * 128, n0 = blockIdx.y * 128;
  const int t = mt >> 1, brow0 = (mt & 1) * 128;
  const int wr = wid >> 1, wc = wid & 1;
  // staging: each gload stages 8 rows x 128B; lane -> (row = lane>>3, slot = lane&7)
  const int srow8 = lane >> 3;
  const int ksrc = ((lane >> 2) & 1) * 32 + 8 * ((lane & 3) ^ ((lane >> 4) & 3));
  const int fr = lane & 15, kb = lane >> 4;
  const int kx = (kb ^ ((fr >> 1) & 3)) * 8;  // swizzled 16B slot within 32-K half
  int aoff[4], boff[4];
#pragma unroll
  for (int f = 0; f < 4; f++) {
    aoff[f] = (wr * 64 + f * 16 + fr) * 64 + kx;
    boff[f] = (wc * 64 + f * 16 + fr) * 64 + kx;
  }
  f32x4 acc[4][4] = {};
#pragma unroll 1
  for (int kk = 0; kk < KBIG_ / 64; kk++) {
    const int k0 = kk * 64;
    const int d = k0 >> 9, h0 = k0 & 511;
    const int p = t + 4 * d;  // S plane; planes [0,40) are zero history
    const u16* Sb = S + (size_t)(p * 256 + brow0) * 512 + h0 + ksrc;
#pragma unroll
    for (int c = 0; c < 4; c++) {
      int rb = c * 32 + wid * 8;
      gload16(Sb + (rb + srow8) * 512, &lA[rb * 64]);
      size_t gb = (size_t)(n0 + rb + srow8) * KBIG_ + k0 + ksrc;
      gload16(Wh + gb, &lBh[rb * 64]);
      gload16(Wl + gb, &lBl[rb * 64]);
    }
    asm volatile("s_waitcnt vmcnt(0)" ::: "memory");
    __syncthreads();
#pragma unroll
    for (int s = 0; s < 2; s++) {
      const int so = s * 32;
      u16x8 bh[4], bl[4];
#pragma unroll
      for (int j = 0; j < 4; j++) {
        bh[j] = *(const u16x8*)&lBh[boff[j] + so];
        bl[j] = *(const u16x8*)&lBl[boff[j] + so];
      }
#pragma unroll
      for (int i = 0; i < 4; i++) {
        u16x8 a = *(const u16x8*)&lA[aoff[i] + so];
#pragma unroll
        for (int j = 0; j < 4; j++) {
          mfma_h(acc[i][j], a, bh[j]);
          mfma_h(acc[i][j], a, bl[j]);
        }
      }
    }
    __syncthreads();
  }
  asm volatile("s_nop 7\n\ts_nop 7" ::: "memory");
#pragma unroll
  for (int i = 0; i < 4; i++) {
    int row = m0 + wr * 64 + i * 16 + (lane >> 4) * 4;
#pragma unroll
    for (int j = 0; j < 4; j++) {
      int col = n0 + wc * 64 + j * 16 + fr;
#pragma unroll
      for (int r = 0; r < 4; r++)
        out[(row + r) * H_ + col] = acc[i][j][r] * (1.0f / 256.0f);  // undo W1 scale
    }
  }
}

// ---------------- GEMM out: curo = gather(S2) @ Wop^T  (BK=64, R3-spk staging pattern) ----------------

__global__ __launch_bounds__(256) void k_gemm_out(const u16* __restrict__ S, const u16* __restrict__ Wh,
                                                  const u16* __restrict__ Wl, float* __restrict__ out) {
  __shared__ alignas(16) u16 lA[128 * 64], lBh[32 * 64], lBl[32 * 64];  // 24 KB
  const int tid = threadIdx.x, lane = tid & 63, wid = tid >> 6;
  const int mt = blockIdx.x;
  const int m0 = mt * 128;
  const int t = mt >> 1, brow0 = (mt & 1) * 128;
  const int srow8 = lane >> 3;
  const int ksrc = ((lane >> 2) & 1) * 32 + 8 * ((lane & 3) ^ ((lane >> 4) & 3));
  const int fr = lane & 15, kb = lane >> 4;
  const int kx = (kb ^ ((fr >> 1) & 3)) * 8;
  int aoff[2], boff[2];
#pragma unroll
  for (int f = 0; f < 2; f++) {
    aoff[f] = (wid * 32 + f * 16 + fr) * 64 + kx;
    boff[f] = (f * 16 + fr) * 64 + kx;
  }
  f32x4 acc[2][2] = {};
#pragma unroll 1
  for (int kk = 0; kk < KBIG_ / 64; kk++) {
    const int k0 = kk * 64;
    const int d = k0 >> 9, h0 = k0 & 511;
    const int p = t + 4 * d;
    const u16* Sb = S + (size_t)(p * 256 + brow0) * 512 + h0 + ksrc;
#pragma unroll
    for (int c = 0; c < 4; c++) {
      int rb = c * 32 + wid * 8;
      gload16(Sb + (rb + srow8) * 512, &lA[rb * 64]);
    }
    gload16(Wh + (size_t)(wid * 8 + srow8) * KBIG_ + k0 + ksrc, &lBh[(wid * 8) * 64]);
    gload16(Wl + (size_t)(wid * 8 + srow8) * KBIG_ + k0 + ksrc, &lBl[(wid * 8) * 64]);
    asm volatile("s_waitcnt vmcnt(0)" ::: "memory");
    __syncthreads();
#pragma unroll
    for (int s = 0; s < 2; s++) {
      const int so = s * 32;
      u16x8 bh[2], bl[2];
#pragma unroll
      for (int j = 0; j < 2; j++) {
        bh[j] = *(const u16x8*)&lBh[boff[j] + so];
        bl[j] = *(const u16x8*)&lBl[boff[j] + so];
      }
#pragma unroll
      for (int i = 0; i < 2; i++) {
        u16x8 a = *(const u16x8*)&lA[aoff[i] + so];
#pragma unroll
        for (int j = 0; j < 2; j++) {
          mfma_h(acc[i][j], a, bh[j]);
          mfma_h(acc[i][j], a, bl[j]);
        }
      }
    }
    __syncthreads();
  }
  asm volatile("s_nop 7\n\ts_nop 7" ::: "memory");
#pragma unroll
  for (int i = 0; i < 2; i++) {
    int row = m0 + wid * 32 + i * 16 + (lane >> 4) * 4;
#pragma unroll
    for (int j = 0; j < 2; j++) {
      int col = j * 16 + fr;
#pragma unroll
      for (int r = 0; r < 4; r++)
        out[(row + r) * NOUTP_ + col] = acc[i][j][r] * (1.0f / 256.0f);  // undo Wo scale
    }
  }
}

// ---------------- elementwise LIF scans (strict fp32 rounding; 5-wide load groups) ----------------

__global__ void k_scan(const float* __restrict__ cur, const float* __restrict__ tau, u16* __restrict__ S) {
  int g = blockIdx.x * 256 + threadIdx.x;   // [0, 131072)
  int b = g >> 9, h = g & 511;
  float a = (float)(1.0 / (1.0 + exp(-(double)tau[h])));
  float mem = 0.f, s = 0.f;
#pragma unroll 1
  for (int tt = 0; tt < 20; tt++) {
    float c[5];
#pragma unroll
    for (int q = 0; q < 5; q++)
      c[q] = cur[((tt * 5 + q) * 256 + b) * 512 + h];   // independent of the recurrence
    u16 sv[5];
#pragma unroll
    for (int q = 0; q < 5; q++) {
      mem = __fadd_rn(__fmul_rn(__fmul_rn(mem, a), __fsub_rn(1.f, s)), c[q]);
      float x = __fsub_rn(mem, THRESH_);
      s = (x > 0.f) ? 1.f : 0.f;
      mem = (mem < THRESH_) ? mem : 0.f;
      sv[q] = (x > 0.f) ? (u16)0x3C00 : (u16)0;  // fp16 1.0
    }
#pragma unroll
    for (int q = 0; q < 5; q++)
      S[((tt * 5 + q + 40) * 256 + b) * 512 + h] = sv[q];
  }
}

__global__ void k_scan_o(const float* __restrict__ curo, const float* __restrict__ tau, float* __restrict__ outp) {
  int b = blockIdx.x * 64 + threadIdx.x;
  if (b >= B_) return;
  float ao[NOUT_], mem[NOUT_], spk[NOUT_], osum[NOUT_], mot[NOUT_];
#pragma unroll
  for (int j = 0; j < NOUT_; j++) {
    ao[j] = (float)(1.0 / (1.0 + exp(-(double)tau[j])));
    mem[j] = 0.f; spk[j] = 0.f; osum[j] = 0.f; mot[j] = 0.f;
  }
#pragma unroll 1
  for (int t = 0; t < WIN_; t++) {
    const float4* rowp = (const float4*)&curo[(t * 256 + b) * NOUTP_];
    float4 v[5];
#pragma unroll
    for (int q = 0; q < 5; q++) v[q] = rowp[q];
    float cv[NOUT_];
#pragma unroll
    for (int q = 0; q < 5; q++) {
      cv[4 * q + 0] = v[q].x; cv[4 * q + 1] = v[q].y;
      cv[4 * q + 2] = v[q].z; cv[4 * q + 3] = v[q].w;
    }
#pragma unroll
    for (int j = 0; j < NOUT_; j++) {
      mem[j] = __fadd_rn(__fmul_rn(__fmul_rn(mem[j], ao[j]), __fsub_rn(1.f, spk[j])), cv[j]);
      float x = __fsub_rn(mem[j], THRESH_);
      spk[j] = (x > 0.f) ? 1.f : 0.f;
      mem[j] = (mem[j] < THRESH_) ? mem[j] : 0.f;
      osum[j] = __fadd_rn(osum[j], spk[j]);
    }
    float mx = -1e30f;
#pragma unroll
    for (int j = 0; j < NOUT_; j++) mx = fmaxf(mx, mem[j]);
    float se = 0.f, e[NOUT_];
#pragma unroll
    for (int j = 0; j < NOUT_; j++) { e[j] = expf(__fsub_rn(mem[j], mx)); se = __fadd_rn(se, e[j]); }
#pragma unroll
    for (int j = 0; j < NOUT_; j++) mot[j] = __fadd_rn(mot[j], __fdiv_rn(e[j], se));
  }
#pragma unroll
  for (int j = 0; j < NOUT_; j++) {
    outp[b * NOUT_ + j] = __fdiv_rn(osum[j], 100.0f);
    outp[B_ * NOUT_ + b * NOUT_ + j] = mot[j];
  }
}

// ---------------- launch ----------------
// Workspace aliasing (liveness-based, ~177MB, proven R5-R10):
//   region0 (72.1MB): Xh+Xl -> dead after k_gemm0 -> cur2 (52.4MB)
//   region1 (52.4MB): cur1  -> dead after scan1   -> S2   (36.7MB)

extern "C" void kernel_launch(void* const* d_in, const int* in_sizes, int n_in,
                              void* d_out, int out_size, void* d_ws, size_t ws_size,
                              hipStream_t stream) {
  const float* in   = (const float*)d_in[0];
  const float* W0   = (const float*)d_in[1];
  const float* W1   = (const float*)d_in[2];
  const float* Wo   = (const float*)d_in[3];
  const float* tau1 = (const float*)d_in[4];
  const float* tau2 = (const float*)d_in[5];
  const float* tauo = (const float*)d_in[6];
  float* out = (float*)d_out;

  char* ws = (char*)d_ws;
  size_t off = 0;
  auto take = [&](size_t bytes) -> char* {
    char* p = ws + off;
    off += (bytes + 255) & ~(size_t)255;
    return p;
  };
  char* region0 = take((size_t)2 * M_ * NINP_ * 2);        // Xh|Xl, later cur2
  u16* Xh  = (u16*)region0;
  u16* Xl  = (u16*)(region0 + (size_t)M_ * NINP_ * 2);
  float* cur2 = (float*)region0;                           // alias (after gemm0)
  char* region1 = take((size_t)M_ * H_ * 4);               // cur1, later S2
  float* cur1 = (float*)region1;
  u16* S2 = (u16*)region1;                                 // alias (after scan1)
  u16* W0h = (u16*)take((size_t)H_ * NINP_ * 2);
  u16* W0l = (u16*)take((size_t)H_ * NINP_ * 2);
  u16* W1h = (u16*)take((size_t)H_ * KBIG_ * 2);
  u16* W1l = (u16*)take((size_t)H_ * KBIG_ * 2);
  u16* Woh = (u16*)take((size_t)NOUTP_ * KBIG_ * 2);
  u16* Wol = (u16*)take((size_t)NOUTP_ * KBIG_ * 2);
  float* curo = (float*)take((size_t)M_ * NOUTP_ * 4);
  u16* S1 = (u16*)take((size_t)PLANES_ * B_ * H_ * 2);     // plain fp16 spikes

  // zero S1 history planes [0,40)
  hipMemsetAsync(S1, 0, (size_t)40 * B_ * H_ * 2, stream);

  k_prep_w<<<dim3(1056), 256, 0, stream>>>(W0, W1, Wo, W0h, W0l, W1h, W1l, Woh, Wol);
  k_split_x<<<dim3(M_ / 4), 256, 0, stream>>>(in, Xh, Xl);

  k_gemm0<<<dim3(200, 4), 256, 0, stream>>>(Xh, Xl, W0h, W0l, cur1);
  k_scan<<<dim3(512), 256, 0, stream>>>(cur1, tau1, S1);
  // cur1 dead; zero S2 history planes [0,40) in its place
  hipMemsetAsync(S2, 0, (size_t)40 * B_ * H_ * 2, stream);
  // Xh/Xl dead; cur2 overwrites region0
  k_gemm_spk<<<dim3(200, 4), 256, 0, stream>>>(S1, W1h, W1l, cur2);
  k_scan<<<dim3(512), 256, 0, stream>>>(cur2, tau2, S2);
  k_gemm_out<<<dim3(200), 256, 0, stream>>>(S2, Woh, Wol, curo);
  k_scan_o<<<dim3(4), 64, 0, stream>>>(curo, tauo, out);
}

// Round 12
// 522.521 us; speedup vs baseline: 1.7231x; 1.2214x over previous
//
#include <hip/hip_runtime.h>
#include <stdint.h>

#define THRESH_ 0.3f
constexpr int B_ = 256, WIN_ = 100, NIN_ = 700, NINP_ = 704, H_ = 512;
constexpr int NOUT_ = 20, NOUTP_ = 32, ND_ = 10, KBIG_ = 5120, M_ = 25600;
constexpr int PLANES_ = 140;   // 40 zero-history + 100

typedef unsigned short u16;
typedef unsigned int u32;
typedef unsigned short u16x4 __attribute__((ext_vector_type(4)));
typedef unsigned short u16x8 __attribute__((ext_vector_type(8)));
typedef float f32x4 __attribute__((ext_vector_type(4)));

// ---- fp16 RNE split ----
__device__ __forceinline__ u16 f2h(float f) {
  _Float16 h = (_Float16)f;           // RNE
  union { _Float16 h; u16 u; } v; v.h = h;
  return v.u;
}
__device__ __forceinline__ float h2f(u16 u) {
  union { u16 u; _Float16 h; } v; v.u = u;
  return (float)v.h;
}

__device__ __forceinline__ void mfma_h(f32x4& acc, u16x8 a, u16x8 b) {
  asm volatile("v_mfma_f32_16x16x32_f16 %0, %1, %2, %0" : "+v"(acc) : "v"(a), "v"(b));
}
__device__ __forceinline__ void gload16(const void* g, void* l) {
  __builtin_amdgcn_global_load_lds(
      (const __attribute__((address_space(1))) unsigned int*)g,
      (__attribute__((address_space(3))) unsigned int*)l, 16, 0, 0);
}

// ---------------- mega prep: one launch for all staging ----------------
// blocks [0,6400):      X split (4 rows/block, float4 vectorized)
// [6400,6912):          W0 split (scaled x256, zero-pad k>=700)
// [6912,7424):          W1 perm+split via LDS transpose (coalesced both sides)
// [7424,7456):          Wo perm+split (rows >=20 zero)
// [7456,7616):          zero S1 history planes (10.25MB... exactly 40*256*512*2B)
// [7616,7776):          zero S2 history planes

__global__ __launch_bounds__(256) void k_prep(const float* __restrict__ in,
                                              const float* __restrict__ W0,
                                              const float* __restrict__ W1,
                                              const float* __restrict__ Wo,
                                              u16* __restrict__ xh, u16* __restrict__ xl,
                                              u16* __restrict__ w0h, u16* __restrict__ w0l,
                                              u16* __restrict__ w1h, u16* __restrict__ w1l,
                                              u16* __restrict__ woh, u16* __restrict__ wol,
                                              u16* __restrict__ S1, u16* __restrict__ S2) {
  __shared__ u16 lh[5120], ll[5120];   // used by W1 part only (20KB)
  int bid = blockIdx.x;
  if (bid < 6400) {
    int r = bid * 4 + (threadIdx.x >> 6);
    int l = threadIdx.x & 63;
    int t = r >> 8, b = r & 255;
    const f32x4* src = (const f32x4*)(in + (size_t)(b * WIN_ + t) * NIN_);
    u16x4* dh = (u16x4*)(xh + (size_t)r * NINP_);
    u16x4* dl = (u16x4*)(xl + (size_t)r * NINP_);
#pragma unroll
    for (int i = 0; i < 3; i++) {
      int k4 = l + 64 * i;
      if (k4 < 176) {
        f32x4 v = (k4 < 175) ? src[k4] : (f32x4){0.f, 0.f, 0.f, 0.f};
        u16x4 hh, lo;
#pragma unroll
        for (int e = 0; e < 4; e++) {
          u16 h = f2h(v[e]);
          hh[e] = h;
          lo[e] = f2h(v[e] - h2f(h));
        }
        dh[k4] = hh;
        dl[k4] = lo;
      }
    }
  } else if (bid < 6912) {
    int j = bid - 6400;
#pragma unroll
    for (int i = 0; i < 3; i++) {
      int k = threadIdx.x + 256 * i;
      if (k < NINP_) {
        float v = (k < NIN_) ? W0[j * NIN_ + k] * 256.0f : 0.f;
        u16 h = f2h(v);
        u16 lo = f2h(v - h2f(h));
        w0h[j * NINP_ + k] = h;
        w0l[j * NINP_ + k] = lo;
      }
    }
  } else if (bid < 7424) {
    int j = bid - 6912;
    // coalesced read (each thread reads 10 contiguous f32 per h), LDS transpose,
    // coalesced u16x4 write. LDS write bank = (h/2)%32 -> 2-way (free).
#pragma unroll
    for (int i = 0; i < 2; i++) {
      int h = threadIdx.x + 256 * i;
      const float* src = W1 + (size_t)j * KBIG_ + h * ND_;
      float v[10];
#pragma unroll
      for (int q = 0; q < 5; q++) {
        float2 p = *(const float2*)(src + 2 * q);
        v[2 * q] = p.x; v[2 * q + 1] = p.y;
      }
#pragma unroll
      for (int d = 0; d < 10; d++) {
        float w = v[d] * 256.0f;
        u16 a = f2h(w);
        u16 c = f2h(w - h2f(a));
        lh[d * 512 + h] = a;
        ll[d * 512 + h] = c;
      }
    }
    __syncthreads();
#pragma unroll
    for (int i = 0; i < 5; i++) {
      int k4 = threadIdx.x + 256 * i;   // [0,1280)
      *(u16x4*)&w1h[(size_t)j * KBIG_ + k4 * 4] = *(const u16x4*)&lh[k4 * 4];
      *(u16x4*)&w1l[(size_t)j * KBIG_ + k4 * 4] = *(const u16x4*)&ll[k4 * 4];
    }
  } else if (bid < 7456) {
    int j = bid - 7424;
#pragma unroll 1
    for (int i = 0; i < 20; i++) {
      int k = threadIdx.x + 256 * i;
      int d = k >> 9, h = k & 511;
      float v = (j < NOUT_) ? Wo[(size_t)j * KBIG_ + h * ND_ + d] * 256.0f : 0.f;
      u16 a = f2h(v);
      u16 b = f2h(v - h2f(a));
      woh[(size_t)j * KBIG_ + k] = a;
      wol[(size_t)j * KBIG_ + k] = b;
    }
  } else {
    u16* dst = (bid < 7616) ? S1 : S2;
    int b0 = (bid < 7616) ? bid - 7456 : bid - 7616;
    f32x4* p = (f32x4*)dst;             // zero 40*256*512*2B = 160 blocks x 16 iters x 4KB
#pragma unroll
    for (int it = 0; it < 16; it++)
      p[(size_t)(b0 * 16 + it) * 256 + threadIdx.x] = (f32x4){0.f, 0.f, 0.f, 0.f};
  }
}

// ---------------- GEMM 0: cur1 = X @ W0^T  (grid (200,4) for XCD affinity) ----------------

__global__ __launch_bounds__(256) void k_gemm0(const u16* __restrict__ Xh, const u16* __restrict__ Xl,
                                               const u16* __restrict__ Wh, const u16* __restrict__ Wl,
                                               float* __restrict__ out) {
  __shared__ alignas(16) u16 lAh[128 * 32], lAl[128 * 32], lBh[128 * 32], lBl[128 * 32];
  const int tid = threadIdx.x, lane = tid & 63, wid = tid >> 6;
  const int m0 = blockIdx.x * 128, n0 = blockIdx.y * 128;
  const int wr = wid >> 1, wc = wid & 1;
  const int srow = lane >> 2;
  const int sk = 8 * ((lane & 3) ^ ((lane >> 3) & 3));  // source-side XOR swizzle (16B units)
  const int fr = lane & 15, kb = lane >> 4;
  int aoff[4], boff[4];
#pragma unroll
  for (int f = 0; f < 4; f++) {
    int row = wr * 64 + f * 16 + fr;
    aoff[f] = row * 32 + (kb ^ ((row >> 1) & 3)) * 8;
    int col = wc * 64 + f * 16 + fr;
    boff[f] = col * 32 + (kb ^ ((col >> 1) & 3)) * 8;
  }
  f32x4 acc[4][4] = {};
#pragma unroll 1
  for (int kk = 0; kk < NINP_ / 32; kk++) {
    const int k0 = kk * 32;
#pragma unroll
    for (int i = 0; i < 2; i++) {
      int c = wid + 4 * i;
      int ga = (m0 + c * 16 + srow) * NINP_ + k0 + sk;
      gload16(Xh + ga, &lAh[c * 512]);
      gload16(Xl + ga, &lAl[c * 512]);
      int gb = (n0 + c * 16 + srow) * NINP_ + k0 + sk;
      gload16(Wh + gb, &lBh[c * 512]);
      gload16(Wl + gb, &lBl[c * 512]);
    }
    asm volatile("s_waitcnt vmcnt(0)" ::: "memory");
    __syncthreads();
    u16x8 bh[4], bl[4];
#pragma unroll
    for (int j = 0; j < 4; j++) {
      bh[j] = *(const u16x8*)&lBh[boff[j]];
      bl[j] = *(const u16x8*)&lBl[boff[j]];
    }
#pragma unroll
    for (int i = 0; i < 4; i++) {
      u16x8 ah = *(const u16x8*)&lAh[aoff[i]];
      u16x8 al = *(const u16x8*)&lAl[aoff[i]];
#pragma unroll
      for (int j = 0; j < 4; j++) {
        mfma_h(acc[i][j], ah, bh[j]);
        mfma_h(acc[i][j], ah, bl[j]);
        mfma_h(acc[i][j], al, bh[j]);
        // al@bl dropped: <= 2^-22 relative, far below fp32 accumulation noise
      }
    }
    __syncthreads();
  }
  asm volatile("s_nop 7\n\ts_nop 7" ::: "memory");
#pragma unroll
  for (int i = 0; i < 4; i++) {
    int row = m0 + wr * 64 + i * 16 + (lane >> 4) * 4;
#pragma unroll
    for (int j = 0; j < 4; j++) {
      int col = n0 + wc * 64 + j * 16 + fr;
#pragma unroll
      for (int r = 0; r < 4; r++)
        out[(row + r) * H_ + col] = acc[i][j][r] * (1.0f / 256.0f);  // undo W0 scale (exact)
    }
  }
}

// ---------------- GEMM spk: cur2 = gather(S1) @ (W1h+W1l)^T  (R10-proven: BK=64 + XCD grid) ----------------

__global__ __launch_bounds__(256) void k_gemm_spk(const u16* __restrict__ S, const u16* __restrict__ Wh,
                                                  const u16* __restrict__ Wl, float* __restrict__ out) {
  __shared__ alignas(16) u16 lA[128 * 64], lBh[128 * 64], lBl[128 * 64];  // 48 KB
  const int tid = threadIdx.x, lane = tid & 63, wid = tid >> 6;
  const int mt = blockIdx.x;                  // grid (200,4): XCD affinity via 200%8==0
  const int m0 = mt * 128, n0 = blockIdx.y * 128;
  const int t = mt >> 1, brow0 = (mt & 1) * 128;
  const int wr = wid >> 1, wc = wid & 1;
  // staging: each gload stages 8 rows x 128B; lane -> (row = lane>>3, slot = lane&7)
  const int srow8 = lane >> 3;
  const int ksrc = ((lane >> 2) & 1) * 32 + 8 * ((lane & 3) ^ ((lane >> 4) & 3));
  const int fr = lane & 15, kb = lane >> 4;
  const int kx = (kb ^ ((fr >> 1) & 3)) * 8;  // swizzled 16B slot within 32-K half
  int aoff[4], boff[4];
#pragma unroll
  for (int f = 0; f < 4; f++) {
    aoff[f] = (wr * 64 + f * 16 + fr) * 64 + kx;
    boff[f] = (wc * 64 + f * 16 + fr) * 64 + kx;
  }
  f32x4 acc[4][4] = {};
#pragma unroll 1
  for (int kk = 0; kk < KBIG_ / 64; kk++) {
    const int k0 = kk * 64;
    const int d = k0 >> 9, h0 = k0 & 511;
    const int p = t + 4 * d;  // S plane; planes [0,40) are zero history
    const u16* Sb = S + (size_t)(p * 256 + brow0) * 512 + h0 + ksrc;
#pragma unroll
    for (int c = 0; c < 4; c++) {
      int rb = c * 32 + wid * 8;
      gload16(Sb + (rb + srow8) * 512, &lA[rb * 64]);
      size_t gb = (size_t)(n0 + rb + srow8) * KBIG_ + k0 + ksrc;
      gload16(Wh + gb, &lBh[rb * 64]);
      gload16(Wl + gb, &lBl[rb * 64]);
    }
    asm volatile("s_waitcnt vmcnt(0)" ::: "memory");
    __syncthreads();
#pragma unroll
    for (int s = 0; s < 2; s++) {
      const int so = s * 32;
      u16x8 bh[4], bl[4];
#pragma unroll
      for (int j = 0; j < 4; j++) {
        bh[j] = *(const u16x8*)&lBh[boff[j] + so];
        bl[j] = *(const u16x8*)&lBl[boff[j] + so];
      }
#pragma unroll
      for (int i = 0; i < 4; i++) {
        u16x8 a = *(const u16x8*)&lA[aoff[i] + so];
#pragma unroll
        for (int j = 0; j < 4; j++) {
          mfma_h(acc[i][j], a, bh[j]);
          mfma_h(acc[i][j], a, bl[j]);
        }
      }
    }
    __syncthreads();
  }
  asm volatile("s_nop 7\n\ts_nop 7" ::: "memory");
#pragma unroll
  for (int i = 0; i < 4; i++) {
    int row = m0 + wr * 64 + i * 16 + (lane >> 4) * 4;
#pragma unroll
    for (int j = 0; j < 4; j++) {
      int col = n0 + wc * 64 + j * 16 + fr;
#pragma unroll
      for (int r = 0; r < 4; r++)
        out[(row + r) * H_ + col] = acc[i][j][r] * (1.0f / 256.0f);  // undo W1 scale
    }
  }
}

// ---------------- GEMM out: curo = gather(S2) @ Wop^T  (BM=64, grid 400 for overlap) ----------------

__global__ __launch_bounds__(256) void k_gemm_out(const u16* __restrict__ S, const u16* __restrict__ Wh,
                                                  const u16* __restrict__ Wl, float* __restrict__ out) {
  __shared__ alignas(16) u16 lA[64 * 64], lBh[32 * 64], lBl[32 * 64];  // 16 KB
  const int tid = threadIdx.x, lane = tid & 63, wid = tid >> 6;
  const int mt = blockIdx.x;                  // [0,400)
  const int m0 = mt * 64;
  const int t = mt >> 2, brow0 = (mt & 3) * 64;
  const int srow8 = lane >> 3;
  const int ksrc = ((lane >> 2) & 1) * 32 + 8 * ((lane & 3) ^ ((lane >> 4) & 3));
  const int fr = lane & 15, kb = lane >> 4;
  const int kx = (kb ^ ((fr >> 1) & 3)) * 8;
  const int aoff = (wid * 16 + fr) * 64 + kx;     // (row>>1)&3 == (fr>>1)&3 since wid*16 is mult of 16
  int boff[2];
#pragma unroll
  for (int f = 0; f < 2; f++) boff[f] = (f * 16 + fr) * 64 + kx;
  f32x4 acc[2] = {};
#pragma unroll 1
  for (int kk = 0; kk < KBIG_ / 64; kk++) {
    const int k0 = kk * 64;
    const int d = k0 >> 9, h0 = k0 & 511;
    const int p = t + 4 * d;
    const u16* Sb = S + (size_t)(p * 256 + brow0) * 512 + h0 + ksrc;
#pragma unroll
    for (int c = 0; c < 2; c++) {
      int rb = c * 32 + wid * 8;                  // rows [0,64)
      gload16(Sb + (rb + srow8) * 512, &lA[rb * 64]);
    }
    gload16(Wh + (size_t)(wid * 8 + srow8) * KBIG_ + k0 + ksrc, &lBh[(wid * 8) * 64]);
    gload16(Wl + (size_t)(wid * 8 + srow8) * KBIG_ + k0 + ksrc, &lBl[(wid * 8) * 64]);
    asm volatile("s_waitcnt vmcnt(0)" ::: "memory");
    __syncthreads();
#pragma unroll
    for (int s = 0; s < 2; s++) {
      const int so = s * 32;
      u16x8 a = *(const u16x8*)&lA[aoff + so];
#pragma unroll
      for (int j = 0; j < 2; j++) {
        u16x8 bh = *(const u16x8*)&lBh[boff[j] + so];
        u16x8 bl = *(const u16x8*)&lBl[boff[j] + so];
        mfma_h(acc[j], a, bh);
        mfma_h(acc[j], a, bl);
      }
    }
    __syncthreads();
  }
  asm volatile("s_nop 7\n\ts_nop 7" ::: "memory");
  {
    int row = m0 + wid * 16 + (lane >> 4) * 4;
#pragma unroll
    for (int j = 0; j < 2; j++) {
      int col = j * 16 + fr;
#pragma unroll
      for (int r = 0; r < 4; r++)
        out[(row + r) * NOUTP_ + col] = acc[j][r] * (1.0f / 256.0f);  // undo Wo scale
    }
  }
}

// ---------------- elementwise LIF scans (strict fp32 rounding; 10-wide load groups) ----------------

__global__ void k_scan(const float* __restrict__ cur, const float* __restrict__ tau, u16* __restrict__ S) {
  int g = blockIdx.x * 256 + threadIdx.x;   // [0, 131072)
  int b = g >> 9, h = g & 511;
  float a = (float)(1.0 / (1.0 + exp(-(double)tau[h])));
  float mem = 0.f, s = 0.f;
#pragma unroll 1
  for (int tt = 0; tt < 10; tt++) {
    float c[10];
#pragma unroll
    for (int q = 0; q < 10; q++)
      c[q] = cur[((tt * 10 + q) * 256 + b) * 512 + h];   // independent of the recurrence
    u16 sv[10];
#pragma unroll
    for (int q = 0; q < 10; q++) {
      mem = __fadd_rn(__fmul_rn(__fmul_rn(mem, a), __fsub_rn(1.f, s)), c[q]);
      float x = __fsub_rn(mem, THRESH_);
      s = (x > 0.f) ? 1.f : 0.f;
      mem = (mem < THRESH_) ? mem : 0.f;
      sv[q] = (x > 0.f) ? (u16)0x3C00 : (u16)0;  // fp16 1.0
    }
#pragma unroll
    for (int q = 0; q < 10; q++)
      S[((tt * 10 + q + 40) * 256 + b) * 512 + h] = sv[q];
  }
}

// wave-parallel output scan: 32-lane group per batch row (20 active lanes),
// shfl-butterfly for softmax max (exact) and sum (tree order; perturbs only out_mot ~1e-7/step)
__global__ void k_scan_o(const float* __restrict__ curo, const float* __restrict__ tau, float* __restrict__ outp) {
  int tid = threadIdx.x;
  int b = blockIdx.x * 8 + (tid >> 5);      // 32 blocks x 8 rows
  int lj = tid & 31;
  bool act = lj < NOUT_;
  float ao = 0.f, mem = 0.f, spk = 0.f, osum = 0.f, mot = 0.f;
  if (act) ao = (float)(1.0 / (1.0 + exp(-(double)tau[lj])));
#pragma unroll 1
  for (int t = 0; t < WIN_; t++) {
    float cv = act ? curo[(size_t)(t * 256 + b) * NOUTP_ + lj] : 0.f;
    mem = __fadd_rn(__fmul_rn(__fmul_rn(mem, ao), __fsub_rn(1.f, spk)), cv);
    float x = __fsub_rn(mem, THRESH_);
    spk = (x > 0.f) ? 1.f : 0.f;
    mem = (mem < THRESH_) ? mem : 0.f;
    if (act) osum = __fadd_rn(osum, spk);
    float mx = act ? mem : -1e30f;
#pragma unroll
    for (int m = 16; m >= 1; m >>= 1) mx = fmaxf(mx, __shfl_xor(mx, m, 32));
    float e = act ? expf(__fsub_rn(mem, mx)) : 0.f;
    float se = e;
#pragma unroll
    for (int m = 16; m >= 1; m >>= 1) se = __fadd_rn(se, __shfl_xor(se, m, 32));
    if (act) mot = __fadd_rn(mot, __fdiv_rn(e, se));
  }
  if (act) {
    outp[b * NOUT_ + lj] = __fdiv_rn(osum, 100.0f);
    outp[B_ * NOUT_ + b * NOUT_ + lj] = mot;
  }
}

// ---------------- launch ----------------
// Workspace (~214MB, R5-proven level): cur2 aliases Xh/Xl (dead after gemm0); S2 own buffer
// so its history-zero can run in the front prep kernel.

extern "C" void kernel_launch(void* const* d_in, const int* in_sizes, int n_in,
                              void* d_out, int out_size, void* d_ws, size_t ws_size,
                              hipStream_t stream) {
  const float* in   = (const float*)d_in[0];
  const float* W0   = (const float*)d_in[1];
  const float* W1   = (const float*)d_in[2];
  const float* Wo   = (const float*)d_in[3];
  const float* tau1 = (const float*)d_in[4];
  const float* tau2 = (const float*)d_in[5];
  const float* tauo = (const float*)d_in[6];
  float* out = (float*)d_out;

  char* ws = (char*)d_ws;
  size_t off = 0;
  auto take = [&](size_t bytes) -> char* {
    char* p = ws + off;
    off += (bytes + 255) & ~(size_t)255;
    return p;
  };
  char* region0 = take((size_t)2 * M_ * NINP_ * 2);        // Xh|Xl, later cur2
  u16* Xh  = (u16*)region0;
  u16* Xl  = (u16*)(region0 + (size_t)M_ * NINP_ * 2);
  float* cur2 = (float*)region0;                           // alias (after gemm0)
  float* cur1 = (float*)take((size_t)M_ * H_ * 4);
  u16* W0h = (u16*)take((size_t)H_ * NINP_ * 2);
  u16* W0l = (u16*)take((size_t)H_ * NINP_ * 2);
  u16* W1h = (u16*)take((size_t)H_ * KBIG_ * 2);
  u16* W1l = (u16*)take((size_t)H_ * KBIG_ * 2);
  u16* Woh = (u16*)take((size_t)NOUTP_ * KBIG_ * 2);
  u16* Wol = (u16*)take((size_t)NOUTP_ * KBIG_ * 2);
  float* curo = (float*)take((size_t)M_ * NOUTP_ * 4);
  u16* S1 = (u16*)take((size_t)PLANES_ * B_ * H_ * 2);     // plain fp16 spikes
  u16* S2 = (u16*)take((size_t)PLANES_ * B_ * H_ * 2);

  k_prep<<<dim3(7776), 256, 0, stream>>>(in, W0, W1, Wo, Xh, Xl, W0h, W0l,
                                         W1h, W1l, Woh, Wol, S1, S2);

  k_gemm0<<<dim3(200, 4), 256, 0, stream>>>(Xh, Xl, W0h, W0l, cur1);
  k_scan<<<dim3(512), 256, 0, stream>>>(cur1, tau1, S1);
  // Xh/Xl dead; cur2 overwrites region0
  k_gemm_spk<<<dim3(200, 4), 256, 0, stream>>>(S1, W1h, W1l, cur2);
  k_scan<<<dim3(512), 256, 0, stream>>>(cur2, tau2, S2);
  k_gemm_out<<<dim3(400), 256, 0, stream>>>(S2, Woh, Wol, curo);
  k_scan_o<<<dim3(32), 256, 0, stream>>>(curo, tauo, out);
}

// Round 13
// 522.509 us; speedup vs baseline: 1.7231x; 1.0000x over previous
//
#include <hip/hip_runtime.h>
#include <stdint.h>

#define THRESH_ 0.3f
constexpr int B_ = 256, WIN_ = 100, NIN_ = 700, NINP_ = 704, H_ = 512;
constexpr int NOUT_ = 20, NOUTP_ = 32, ND_ = 10, KBIG_ = 5120, M_ = 25600;
constexpr int PLANES_ = 140;   // 40 zero-history + 100

typedef unsigned short u16;
typedef unsigned int u32;
typedef unsigned short u16x4 __attribute__((ext_vector_type(4)));
typedef unsigned short u16x8 __attribute__((ext_vector_type(8)));
typedef float f32x4 __attribute__((ext_vector_type(4)));

// ---- fp16 RNE split ----
__device__ __forceinline__ u16 f2h(float f) {
  _Float16 h = (_Float16)f;           // RNE
  union { _Float16 h; u16 u; } v; v.h = h;
  return v.u;
}
__device__ __forceinline__ float h2f(u16 u) {
  union { u16 u; _Float16 h; } v; v.u = u;
  return (float)v.h;
}

__device__ __forceinline__ void mfma_h(f32x4& acc, u16x8 a, u16x8 b) {
  asm volatile("v_mfma_f32_16x16x32_f16 %0, %1, %2, %0" : "+v"(acc) : "v"(a), "v"(b));
}
__device__ __forceinline__ void gload16(const void* g, void* l) {
  __builtin_amdgcn_global_load_lds(
      (const __attribute__((address_space(1))) unsigned int*)g,
      (__attribute__((address_space(3))) unsigned int*)l, 16, 0, 0);
}

// ---------------- mega prep: one launch for all staging ----------------
// blocks [0,6400):      X split (4 rows/block, float4 vectorized)
// [6400,6912):          W0 split (scaled x256, zero-pad k>=700)
// [6912,7424):          W1 perm+split via LDS transpose (coalesced both sides)
// [7424,7456):          Wo perm+split (rows >=20 zero)
// [7456,7616):          zero S1 history planes
// [7616,7776):          zero S2 history planes

__global__ __launch_bounds__(256) void k_prep(const float* __restrict__ in,
                                              const float* __restrict__ W0,
                                              const float* __restrict__ W1,
                                              const float* __restrict__ Wo,
                                              u16* __restrict__ xh, u16* __restrict__ xl,
                                              u16* __restrict__ w0h, u16* __restrict__ w0l,
                                              u16* __restrict__ w1h, u16* __restrict__ w1l,
                                              u16* __restrict__ woh, u16* __restrict__ wol,
                                              u16* __restrict__ S1, u16* __restrict__ S2) {
  __shared__ u16 lh[5120], ll[5120];   // used by W1 part only (20KB)
  int bid = blockIdx.x;
  if (bid < 6400) {
    int r = bid * 4 + (threadIdx.x >> 6);
    int l = threadIdx.x & 63;
    int t = r >> 8, b = r & 255;
    const f32x4* src = (const f32x4*)(in + (size_t)(b * WIN_ + t) * NIN_);
    u16x4* dh = (u16x4*)(xh + (size_t)r * NINP_);
    u16x4* dl = (u16x4*)(xl + (size_t)r * NINP_);
#pragma unroll
    for (int i = 0; i < 3; i++) {
      int k4 = l + 64 * i;
      if (k4 < 176) {
        f32x4 v = (k4 < 175) ? src[k4] : (f32x4){0.f, 0.f, 0.f, 0.f};
        u16x4 hh, lo;
#pragma unroll
        for (int e = 0; e < 4; e++) {
          u16 h = f2h(v[e]);
          hh[e] = h;
          lo[e] = f2h(v[e] - h2f(h));
        }
        dh[k4] = hh;
        dl[k4] = lo;
      }
    }
  } else if (bid < 6912) {
    int j = bid - 6400;
#pragma unroll
    for (int i = 0; i < 3; i++) {
      int k = threadIdx.x + 256 * i;
      if (k < NINP_) {
        float v = (k < NIN_) ? W0[j * NIN_ + k] * 256.0f : 0.f;
        u16 h = f2h(v);
        u16 lo = f2h(v - h2f(h));
        w0h[j * NINP_ + k] = h;
        w0l[j * NINP_ + k] = lo;
      }
    }
  } else if (bid < 7424) {
    int j = bid - 6912;
    // coalesced read (each thread reads 10 contiguous f32 per h), LDS transpose,
    // coalesced u16x4 write. LDS write bank = (h/2)%32 -> 2-way (free).
#pragma unroll
    for (int i = 0; i < 2; i++) {
      int h = threadIdx.x + 256 * i;
      const float* src = W1 + (size_t)j * KBIG_ + h * ND_;
      float v[10];
#pragma unroll
      for (int q = 0; q < 5; q++) {
        float2 p = *(const float2*)(src + 2 * q);
        v[2 * q] = p.x; v[2 * q + 1] = p.y;
      }
#pragma unroll
      for (int d = 0; d < 10; d++) {
        float w = v[d] * 256.0f;
        u16 a = f2h(w);
        u16 c = f2h(w - h2f(a));
        lh[d * 512 + h] = a;
        ll[d * 512 + h] = c;
      }
    }
    __syncthreads();
#pragma unroll
    for (int i = 0; i < 5; i++) {
      int k4 = threadIdx.x + 256 * i;   // [0,1280)
      *(u16x4*)&w1h[(size_t)j * KBIG_ + k4 * 4] = *(const u16x4*)&lh[k4 * 4];
      *(u16x4*)&w1l[(size_t)j * KBIG_ + k4 * 4] = *(const u16x4*)&ll[k4 * 4];
    }
  } else if (bid < 7456) {
    int j = bid - 7424;
#pragma unroll 1
    for (int i = 0; i < 20; i++) {
      int k = threadIdx.x + 256 * i;
      int d = k >> 9, h = k & 511;
      float v = (j < NOUT_) ? Wo[(size_t)j * KBIG_ + h * ND_ + d] * 256.0f : 0.f;
      u16 a = f2h(v);
      u16 b = f2h(v - h2f(a));
      woh[(size_t)j * KBIG_ + k] = a;
      wol[(size_t)j * KBIG_ + k] = b;
    }
  } else {
    u16* dst = (bid < 7616) ? S1 : S2;
    int b0 = (bid < 7616) ? bid - 7456 : bid - 7616;
    f32x4* p = (f32x4*)dst;             // zero 40*256*512*2B = 160 blocks x 16 iters x 4KB
#pragma unroll
    for (int it = 0; it < 16; it++)
      p[(size_t)(b0 * 16 + it) * 256 + threadIdx.x] = (f32x4){0.f, 0.f, 0.f, 0.f};
  }
}

// ---------------- GEMM 0: cur1 = X @ W0^T  (grid (200,4) for XCD affinity) ----------------

__global__ __launch_bounds__(256) void k_gemm0(const u16* __restrict__ Xh, const u16* __restrict__ Xl,
                                               const u16* __restrict__ Wh, const u16* __restrict__ Wl,
                                               float* __restrict__ out) {
  __shared__ alignas(16) u16 lAh[128 * 32], lAl[128 * 32], lBh[128 * 32], lBl[128 * 32];
  const int tid = threadIdx.x, lane = tid & 63, wid = tid >> 6;
  const int m0 = blockIdx.x * 128, n0 = blockIdx.y * 128;
  const int wr = wid >> 1, wc = wid & 1;
  const int srow = lane >> 2;
  const int sk = 8 * ((lane & 3) ^ ((lane >> 3) & 3));  // source-side XOR swizzle (16B units)
  const int fr = lane & 15, kb = lane >> 4;
  int aoff[4], boff[4];
#pragma unroll
  for (int f = 0; f < 4; f++) {
    int row = wr * 64 + f * 16 + fr;
    aoff[f] = row * 32 + (kb ^ ((row >> 1) & 3)) * 8;
    int col = wc * 64 + f * 16 + fr;
    boff[f] = col * 32 + (kb ^ ((col >> 1) & 3)) * 8;
  }
  f32x4 acc[4][4] = {};
#pragma unroll 1
  for (int kk = 0; kk < NINP_ / 32; kk++) {
    const int k0 = kk * 32;
#pragma unroll
    for (int i = 0; i < 2; i++) {
      int c = wid + 4 * i;
      int ga = (m0 + c * 16 + srow) * NINP_ + k0 + sk;
      gload16(Xh + ga, &lAh[c * 512]);
      gload16(Xl + ga, &lAl[c * 512]);
      int gb = (n0 + c * 16 + srow) * NINP_ + k0 + sk;
      gload16(Wh + gb, &lBh[c * 512]);
      gload16(Wl + gb, &lBl[c * 512]);
    }
    asm volatile("s_waitcnt vmcnt(0)" ::: "memory");
    __syncthreads();
    u16x8 bh[4], bl[4];
#pragma unroll
    for (int j = 0; j < 4; j++) {
      bh[j] = *(const u16x8*)&lBh[boff[j]];
      bl[j] = *(const u16x8*)&lBl[boff[j]];
    }
#pragma unroll
    for (int i = 0; i < 4; i++) {
      u16x8 ah = *(const u16x8*)&lAh[aoff[i]];
      u16x8 al = *(const u16x8*)&lAl[aoff[i]];
#pragma unroll
      for (int j = 0; j < 4; j++) {
        mfma_h(acc[i][j], ah, bh[j]);
        mfma_h(acc[i][j], ah, bl[j]);
        mfma_h(acc[i][j], al, bh[j]);
        // al@bl dropped: <= 2^-22 relative, far below fp32 accumulation noise
      }
    }
    __syncthreads();
  }
  asm volatile("s_nop 7\n\ts_nop 7" ::: "memory");
#pragma unroll
  for (int i = 0; i < 4; i++) {
    int row = m0 + wr * 64 + i * 16 + (lane >> 4) * 4;
#pragma unroll
    for (int j = 0; j < 4; j++) {
      int col = n0 + wc * 64 + j * 16 + fr;
#pragma unroll
      for (int r = 0; r < 4; r++)
        out[(row + r) * H_ + col] = acc[i][j][r] * (1.0f / 256.0f);  // undo W0 scale (exact)
    }
  }
}

// ---------------- GEMM spk: cur2 = gather(S1) @ (W1h+W1l)^T  (R10-proven: BK=64 + XCD grid) ----------------

__global__ __launch_bounds__(256) void k_gemm_spk(const u16* __restrict__ S, const u16* __restrict__ Wh,
                                                  const u16* __restrict__ Wl, float* __restrict__ out) {
  __shared__ alignas(16) u16 lA[128 * 64], lBh[128 * 64], lBl[128 * 64];  // 48 KB
  const int tid = threadIdx.x, lane = tid & 63, wid = tid >> 6;
  const int mt = blockIdx.x;                  // grid (200,4): XCD affinity via 200%8==0
  const int m0 = mt * 128, n0 = blockIdx.y * 128;
  const int t = mt >> 1, brow0 = (mt & 1) * 128;
  const int wr = wid >> 1, wc = wid & 1;
  // staging: each gload stages 8 rows x 128B; lane -> (row = lane>>3, slot = lane&7)
  const int srow8 = lane >> 3;
  const int ksrc = ((lane >> 2) & 1) * 32 + 8 * ((lane & 3) ^ ((lane >> 4) & 3));
  const int fr = lane & 15, kb = lane >> 4;
  const int kx = (kb ^ ((fr >> 1) & 3)) * 8;  // swizzled 16B slot within 32-K half
  int aoff[4], boff[4];
#pragma unroll
  for (int f = 0; f < 4; f++) {
    aoff[f] = (wr * 64 + f * 16 + fr) * 64 + kx;
    boff[f] = (wc * 64 + f * 16 + fr) * 64 + kx;
  }
  f32x4 acc[4][4] = {};
#pragma unroll 1
  for (int kk = 0; kk < KBIG_ / 64; kk++) {
    const int k0 = kk * 64;
    const int d = k0 >> 9, h0 = k0 & 511;
    const int p = t + 4 * d;  // S plane; planes [0,40) are zero history
    const u16* Sb = S + (size_t)(p * 256 + brow0) * 512 + h0 + ksrc;
#pragma unroll
    for (int c = 0; c < 4; c++) {
      int rb = c * 32 + wid * 8;
      gload16(Sb + (rb + srow8) * 512, &lA[rb * 64]);
      size_t gb = (size_t)(n0 + rb + srow8) * KBIG_ + k0 + ksrc;
      gload16(Wh + gb, &lBh[rb * 64]);
      gload16(Wl + gb, &lBl[rb * 64]);
    }
    asm volatile("s_waitcnt vmcnt(0)" ::: "memory");
    __syncthreads();
#pragma unroll
    for (int s = 0; s < 2; s++) {
      const int so = s * 32;
      u16x8 bh[4], bl[4];
#pragma unroll
      for (int j = 0; j < 4; j++) {
        bh[j] = *(const u16x8*)&lBh[boff[j] + so];
        bl[j] = *(const u16x8*)&lBl[boff[j] + so];
      }
#pragma unroll
      for (int i = 0; i < 4; i++) {
        u16x8 a = *(const u16x8*)&lA[aoff[i] + so];
#pragma unroll
        for (int j = 0; j < 4; j++) {
          mfma_h(acc[i][j], a, bh[j]);
          mfma_h(acc[i][j], a, bl[j]);
        }
      }
    }
    __syncthreads();
  }
  asm volatile("s_nop 7\n\ts_nop 7" ::: "memory");
#pragma unroll
  for (int i = 0; i < 4; i++) {
    int row = m0 + wr * 64 + i * 16 + (lane >> 4) * 4;
#pragma unroll
    for (int j = 0; j < 4; j++) {
      int col = n0 + wc * 64 + j * 16 + fr;
#pragma unroll
      for (int r = 0; r < 4; r++)
        out[(row + r) * H_ + col] = acc[i][j][r] * (1.0f / 256.0f);  // undo W1 scale
    }
  }
}

// ---------------- GEMM out: curo = gather(S2) @ Wop^T  (BM=64, grid 400 for overlap) ----------------

__global__ __launch_bounds__(256) void k_gemm_out(const u16* __restrict__ S, const u16* __restrict__ Wh,
                                                  const u16* __restrict__ Wl, float* __restrict__ out) {
  __shared__ alignas(16) u16 lA[64 * 64], lBh[32 * 64], lBl[32 * 64];  // 16 KB
  const int tid = threadIdx.x, lane = tid & 63, wid = tid >> 6;
  const int mt = blockIdx.x;                  // [0,400)
  const int m0 = mt * 64;
  const int t = mt >> 2, brow0 = (mt & 3) * 64;
  const int srow8 = lane >> 3;
  const int ksrc = ((lane >> 2) & 1) * 32 + 8 * ((lane & 3) ^ ((lane >> 4) & 3));
  const int fr = lane & 15, kb = lane >> 4;
  const int kx = (kb ^ ((fr >> 1) & 3)) * 8;
  const int aoff = (wid * 16 + fr) * 64 + kx;     // (row>>1)&3 == (fr>>1)&3 since wid*16 is mult of 16
  int boff[2];
#pragma unroll
  for (int f = 0; f < 2; f++) boff[f] = (f * 16 + fr) * 64 + kx;
  f32x4 acc[2] = {};
#pragma unroll 1
  for (int kk = 0; kk < KBIG_ / 64; kk++) {
    const int k0 = kk * 64;
    const int d = k0 >> 9, h0 = k0 & 511;
    const int p = t + 4 * d;
    const u16* Sb = S + (size_t)(p * 256 + brow0) * 512 + h0 + ksrc;
#pragma unroll
    for (int c = 0; c < 2; c++) {
      int rb = c * 32 + wid * 8;                  // rows [0,64)
      gload16(Sb + (rb + srow8) * 512, &lA[rb * 64]);
    }
    gload16(Wh + (size_t)(wid * 8 + srow8) * KBIG_ + k0 + ksrc, &lBh[(wid * 8) * 64]);
    gload16(Wl + (size_t)(wid * 8 + srow8) * KBIG_ + k0 + ksrc, &lBl[(wid * 8) * 64]);
    asm volatile("s_waitcnt vmcnt(0)" ::: "memory");
    __syncthreads();
#pragma unroll
    for (int s = 0; s < 2; s++) {
      const int so = s * 32;
      u16x8 a = *(const u16x8*)&lA[aoff + so];
#pragma unroll
      for (int j = 0; j < 2; j++) {
        u16x8 bh = *(const u16x8*)&lBh[boff[j] + so];
        u16x8 bl = *(const u16x8*)&lBl[boff[j] + so];
        mfma_h(acc[j], a, bh);
        mfma_h(acc[j], a, bl);
      }
    }
    __syncthreads();
  }
  asm volatile("s_nop 7\n\ts_nop 7" ::: "memory");
  {
    int row = m0 + wid * 16 + (lane >> 4) * 4;
#pragma unroll
    for (int j = 0; j < 2; j++) {
      int col = j * 16 + fr;
#pragma unroll
      for (int r = 0; r < 4; r++)
        out[(row + r) * NOUTP_ + col] = acc[j][r] * (1.0f / 256.0f);  // undo Wo scale
    }
  }
}

// ---------------- elementwise LIF scans (strict fp32 rounding; 20-wide load groups) ----------------

__global__ void k_scan(const float* __restrict__ cur, const float* __restrict__ tau, u16* __restrict__ S) {
  int g = blockIdx.x * 256 + threadIdx.x;   // [0, 131072)
  int b = g >> 9, h = g & 511;
  float a = (float)(1.0 / (1.0 + exp(-(double)tau[h])));
  float mem = 0.f, s = 0.f;
#pragma unroll 1
  for (int tt = 0; tt < 5; tt++) {
    float c[20];
#pragma unroll
    for (int q = 0; q < 20; q++)
      c[q] = cur[((tt * 20 + q) * 256 + b) * 512 + h];   // independent of the recurrence
    u16 sv[20];
#pragma unroll
    for (int q = 0; q < 20; q++) {
      mem = __fadd_rn(__fmul_rn(__fmul_rn(mem, a), __fsub_rn(1.f, s)), c[q]);
      float x = __fsub_rn(mem, THRESH_);
      s = (x > 0.f) ? 1.f : 0.f;
      mem = (mem < THRESH_) ? mem : 0.f;
      sv[q] = (x > 0.f) ? (u16)0x3C00 : (u16)0;  // fp16 1.0
    }
#pragma unroll
    for (int q = 0; q < 20; q++)
      S[((tt * 20 + q + 40) * 256 + b) * 512 + h] = sv[q];
  }
}

// wave-parallel output scan: 32-lane group per batch row (20 active lanes),
// shfl-butterfly for softmax max (exact) and sum (tree order; perturbs only out_mot ~1e-7/step)
__global__ void k_scan_o(const float* __restrict__ curo, const float* __restrict__ tau, float* __restrict__ outp) {
  int tid = threadIdx.x;
  int b = blockIdx.x * 8 + (tid >> 5);      // 32 blocks x 8 rows
  int lj = tid & 31;
  bool act = lj < NOUT_;
  float ao = 0.f, mem = 0.f, spk = 0.f, osum = 0.f, mot = 0.f;
  if (act) ao = (float)(1.0 / (1.0 + exp(-(double)tau[lj])));
#pragma unroll 1
  for (int t = 0; t < WIN_; t++) {
    float cv = act ? curo[(size_t)(t * 256 + b) * NOUTP_ + lj] : 0.f;
    mem = __fadd_rn(__fmul_rn(__fmul_rn(mem, ao), __fsub_rn(1.f, spk)), cv);
    float x = __fsub_rn(mem, THRESH_);
    spk = (x > 0.f) ? 1.f : 0.f;
    mem = (mem < THRESH_) ? mem : 0.f;
    if (act) osum = __fadd_rn(osum, spk);
    float mx = act ? mem : -1e30f;
#pragma unroll
    for (int m = 16; m >= 1; m >>= 1) mx = fmaxf(mx, __shfl_xor(mx, m, 32));
    float e = act ? expf(__fsub_rn(mem, mx)) : 0.f;
    float se = e;
#pragma unroll
    for (int m = 16; m >= 1; m >>= 1) se = __fadd_rn(se, __shfl_xor(se, m, 32));
    if (act) mot = __fadd_rn(mot, __fdiv_rn(e, se));
  }
  if (act) {
    outp[b * NOUT_ + lj] = __fdiv_rn(osum, 100.0f);
    outp[B_ * NOUT_ + b * NOUT_ + lj] = mot;
  }
}

// ---------------- launch ----------------
// Workspace (~214MB, R5-proven level): cur2 aliases Xh/Xl (dead after gemm0); S2 own buffer
// so its history-zero runs in the front prep kernel.

extern "C" void kernel_launch(void* const* d_in, const int* in_sizes, int n_in,
                              void* d_out, int out_size, void* d_ws, size_t ws_size,
                              hipStream_t stream) {
  const float* in   = (const float*)d_in[0];
  const float* W0   = (const float*)d_in[1];
  const float* W1   = (const float*)d_in[2];
  const float* Wo   = (const float*)d_in[3];
  const float* tau1 = (const float*)d_in[4];
  const float* tau2 = (const float*)d_in[5];
  const float* tauo = (const float*)d_in[6];
  float* out = (float*)d_out;

  char* ws = (char*)d_ws;
  size_t off = 0;
  auto take = [&](size_t bytes) -> char* {
    char* p = ws + off;
    off += (bytes + 255) & ~(size_t)255;
    return p;
  };
  char* region0 = take((size_t)2 * M_ * NINP_ * 2);        // Xh|Xl, later cur2
  u16* Xh  = (u16*)region0;
  u16* Xl  = (u16*)(region0 + (size_t)M_ * NINP_ * 2);
  float* cur2 = (float*)region0;                           // alias (after gemm0)
  float* cur1 = (float*)take((size_t)M_ * H_ * 4);
  u16* W0h = (u16*)take((size_t)H_ * NINP_ * 2);
  u16* W0l = (u16*)take((size_t)H_ * NINP_ * 2);
  u16* W1h = (u16*)take((size_t)H_ * KBIG_ * 2);
  u16* W1l = (u16*)take((size_t)H_ * KBIG_ * 2);
  u16* Woh = (u16*)take((size_t)NOUTP_ * KBIG_ * 2);
  u16* Wol = (u16*)take((size_t)NOUTP_ * KBIG_ * 2);
  float* curo = (float*)take((size_t)M_ * NOUTP_ * 4);
  u16* S1 = (u16*)take((size_t)PLANES_ * B_ * H_ * 2);     // plain fp16 spikes
  u16* S2 = (u16*)take((size_t)PLANES_ * B_ * H_ * 2);

  k_prep<<<dim3(7776), 256, 0, stream>>>(in, W0, W1, Wo, Xh, Xl, W0h, W0l,
                                         W1h, W1l, Woh, Wol, S1, S2);

  k_gemm0<<<dim3(200, 4), 256, 0, stream>>>(Xh, Xl, W0h, W0l, cur1);
  k_scan<<<dim3(512), 256, 0, stream>>>(cur1, tau1, S1);
  // Xh/Xl dead; cur2 overwrites region0
  k_gemm_spk<<<dim3(200, 4), 256, 0, stream>>>(S1, W1h, W1l, cur2);
  k_scan<<<dim3(512), 256, 0, stream>>>(cur2, tau2, S2);
  k_gemm_out<<<dim3(400), 256, 0, stream>>>(S2, Woh, Wol, curo);
  k_scan_o<<<dim3(32), 256, 0, stream>>>(curo, tauo, out);
}